// Round 2
// baseline (3990.293 us; speedup 1.0000x reference)
//
#include <hip/hip_runtime.h>

typedef long long LL;

// ---- problem constants ----
constexpr int CDIM  = 768;
constexpr int HEADS = 12;
constexpr int LT    = 64;    // template tokens
constexpr int LS    = 256;   // search tokens
constexpr int NTOK  = 320;
constexpr int BATCH = 32;
constexpr int HID   = 3072;
constexpr int LKEEP = 180;   // ceil(0.7*256)
constexpr int LREM  = 76;
constexpr int NK    = 244;   // LT + LKEEP

// ---- d_out element offsets (all f32) ----
constexpr LL O_XRGB = 0;                         // 32*244*768
constexpr LL O_XTIR = 5996544;
constexpr LL O_GIT  = 11993088;                  // 32*64
constexpr LL O_GSN  = 11995136;                  // 32*180
constexpr LL O_REM  = 12000896;                  // 32*76
constexpr LL O_CR   = 12003328;                  // 32*12*320*320
constexpr LL O_CT   = 51324928;
constexpr LL O_JS   = 90646528;

// ---- workspace float offsets ----
constexpr LL W_X1   = 0;          // 2*32*320*768 = 15728640
constexpr LL W_X1G  = 15728640;   // 2*32*244*768 = 11993088
constexpr LL W_SC   = 27721728;   // 32*256 DOUBLES (occupies 16384 floats)
constexpr LL W_ORD  = 27738112;   // 32*256 ints
constexpr LL W_XN   = 27746304;   // 32*320*768 = 7864320 (also LN2 out)
constexpr LL W_QKV  = 35610624;   // max(QKV 23592960, H1 23986176)
constexpr LL W_ATT  = 59596800;   // 32*320*768

// =======================================================================
// LayerNorm: one block per 768-elem row
// =======================================================================
__global__ __launch_bounds__(256)
void ln_kernel(const float* __restrict__ x, const float* __restrict__ g,
               const float* __restrict__ bta, float* __restrict__ y)
{
    LL row = blockIdx.x;
    const float* xr = x + row * 768;
    float* yr = y + row * 768;
    int t = threadIdx.x;
    float v0 = xr[t], v1 = xr[t + 256], v2 = xr[t + 512];
    __shared__ float red[256];
    red[t] = v0 + v1 + v2;
    __syncthreads();
    for (int s = 128; s; s >>= 1) { if (t < s) red[t] += red[t + s]; __syncthreads(); }
    float mean = red[0] / 768.0f;
    __syncthreads();
    float d0 = v0 - mean, d1 = v1 - mean, d2 = v2 - mean;
    red[t] = d0 * d0 + d1 * d1 + d2 * d2;
    __syncthreads();
    for (int s = 128; s; s >>= 1) { if (t < s) red[t] += red[t + s]; __syncthreads(); }
    float var = red[0] / 768.0f;
    float rs = 1.0f / sqrtf(var + 1e-5f);
    yr[t]       = d0 * rs * g[t]       + bta[t];
    yr[t + 256] = d1 * rs * g[t + 256] + bta[t + 256];
    yr[t + 512] = d2 * rs * g[t + 512] + bta[t + 512];
}

// =======================================================================
// Tiled f32 GEMM.  C[M,N] = A[M,K] * op(B)  (+bias)(gelu)(+res), *scale
// TRANSB: B is [N,K] row-major (X @ W^T).  else B is [K,N] row-major.
// Batched over blockIdx.z: zb=z/divH, zh=z%divH; pointer offsets added.
// Requires M%64==0, N%64==0, K%16==0 (all shapes here satisfy this).
// =======================================================================
template<bool TRANSB>
__global__ __launch_bounds__(256)
void gemm_f32(const float* __restrict__ A, const float* __restrict__ B,
              float* __restrict__ C, const float* __restrict__ bias,
              const float* __restrict__ res,
              int M, int N, int K, int lda, int ldb, int ldc, int ldres,
              int divH, LL sA1, LL sA2, LL sB1, LL sB2, LL sC1, LL sC2, LL sRes1,
              float scale, int act)
{
    int z = blockIdx.z;
    int zb = z / divH, zh = z - zb * divH;
    A += zb * sA1 + zh * sA2;
    B += zb * sB1 + zh * sB2;
    C += zb * sC1 + zh * sC2;
    if (res) res += zb * sRes1;

    __shared__ float As[16][68];
    __shared__ float Bs[16][68];
    const int t  = threadIdx.x;
    const int tx = t & 15, ty = t >> 4;
    const int bm = blockIdx.y * 64, bn = blockIdx.x * 64;

    const int lr = t >> 2;           // tile row for A / NT-B loads (0..63)
    const int lk = (t & 3) * 4;      // k offset (0,4,8,12)
    const int nr = t >> 4;           // NN-B row (0..15)
    const int nc = (t & 15) * 4;     // NN-B col

    float acc[4][4] = {};

    for (int k0 = 0; k0 < K; k0 += 16) {
        float4 av = *(const float4*)(A + (LL)(bm + lr) * lda + (k0 + lk));
        float4 bv;
        if (TRANSB) bv = *(const float4*)(B + (LL)(bn + lr) * ldb + (k0 + lk));
        else        bv = *(const float4*)(B + (LL)(k0 + nr) * ldb + (bn + nc));
        __syncthreads();
        As[lk + 0][lr] = av.x; As[lk + 1][lr] = av.y;
        As[lk + 2][lr] = av.z; As[lk + 3][lr] = av.w;
        if (TRANSB) {
            Bs[lk + 0][lr] = bv.x; Bs[lk + 1][lr] = bv.y;
            Bs[lk + 2][lr] = bv.z; Bs[lk + 3][lr] = bv.w;
        } else {
            *(float4*)&Bs[nr][nc] = bv;
        }
        __syncthreads();
        #pragma unroll
        for (int k = 0; k < 16; ++k) {
            float4 af = *(const float4*)&As[k][ty * 4];
            float4 bf = *(const float4*)&Bs[k][tx * 4];
            float ar[4] = {af.x, af.y, af.z, af.w};
            float br[4] = {bf.x, bf.y, bf.z, bf.w};
            #pragma unroll
            for (int i = 0; i < 4; ++i)
                #pragma unroll
                for (int j = 0; j < 4; ++j)
                    acc[i][j] = fmaf(ar[i], br[j], acc[i][j]);
        }
    }

    #pragma unroll
    for (int i = 0; i < 4; ++i) {
        int gm = bm + ty * 4 + i;
        #pragma unroll
        for (int j = 0; j < 4; ++j) {
            int gn = bn + tx * 4 + j;
            float v = acc[i][j] * scale;
            if (bias) v += bias[gn];
            if (act)  v = 0.5f * v * (erff(v * 0.70710678118654752f) + 1.0f);
            if (res)  v += res[(LL)gm * ldres + gn];
            C[(LL)gm * ldc + gn] = v;
        }
    }
}

// =======================================================================
// In-place row softmax over 320 elems; 1 wave per row, 4 rows per block
// =======================================================================
__global__ __launch_bounds__(256)
void softmax_kernel(float* __restrict__ p)
{
    LL row = (LL)blockIdx.x * 4 + (threadIdx.x >> 6);
    int lane = threadIdx.x & 63;
    float* pr = p + row * 320;
    float v[5];
    #pragma unroll
    for (int i = 0; i < 5; ++i) v[i] = pr[lane + i * 64];
    float mx = v[0];
    #pragma unroll
    for (int i = 1; i < 5; ++i) mx = fmaxf(mx, v[i]);
    for (int o = 32; o; o >>= 1) mx = fmaxf(mx, __shfl_down(mx, o, 64));
    mx = __shfl(mx, 0, 64);
    float e[5], s = 0.0f;
    #pragma unroll
    for (int i = 0; i < 5; ++i) { e[i] = expf(v[i] - mx); s += e[i]; }
    for (int o = 32; o; o >>= 1) s += __shfl_down(s, o, 64);
    s = __shfl(s, 0, 64);
    #pragma unroll
    for (int i = 0; i < 5; ++i) pr[lane + i * 64] = e[i] / s;
}

// =======================================================================
// scores[b][j] = mean_h ( sum_t (corr_rgb+corr_tir)[b,h,t,64+j] / 64 )
// FULL F64 accumulation: score noise ~2e-10 (vs ~1e-7 for seq f32),
// matching the reference's own noise floor so near-tie ordering agrees.
// =======================================================================
__global__ __launch_bounds__(256)
void score_reduce(const float* __restrict__ c0, const float* __restrict__ c1,
                  double* __restrict__ scores)
{
    int b = blockIdx.x, j = threadIdx.x;
    const float* p0 = c0 + (LL)b * HEADS * NTOK * NTOK + LT + j;
    const float* p1 = c1 + (LL)b * HEADS * NTOK * NTOK + LT + j;
    double acc = 0.0;
    for (int h = 0; h < HEADS; ++h) {
        const float* q0 = p0 + (LL)h * NTOK * NTOK;
        const float* q1 = p1 + (LL)h * NTOK * NTOK;
        double ah = 0.0;
        for (int tq = 0; tq < LT; ++tq)
            ah += (double)q0[tq * NTOK] + (double)q1[tq * NTOK];
        acc += ah / 64.0;
    }
    scores[b * 256 + j] = acc / 12.0;
}

// =======================================================================
// Stable descending argsort via rank counting on F64 scores; writes
// ordered index outputs (as floats) and full order list for the gather.
// =======================================================================
__global__ __launch_bounds__(256)
void rank_kernel(const double* __restrict__ scores, const int* __restrict__ gis,
                 int* __restrict__ ord, float* __restrict__ onew, float* __restrict__ orem)
{
    int b = blockIdx.x, j = threadIdx.x;
    __shared__ double s[256];
    s[j] = scores[b * 256 + j];
    __syncthreads();
    double sj = s[j];
    int r = 0;
    for (int i = 0; i < 256; ++i) {
        double si = s[i];
        r += (si > sj) || (si == sj && i < j);
    }
    ord[b * 256 + r] = j;
    float gv = (float)gis[b * 256 + j];
    if (r < LKEEP) onew[b * LKEEP + r] = gv;
    else           orem[b * LREM + (r - LKEEP)] = gv;
}

__global__ void copy_misc(const int* __restrict__ git, const float* __restrict__ js,
                          float* __restrict__ out)
{
    int i = blockIdx.x * 256 + threadIdx.x;
    if (i < 2048)      out[O_GIT + i] = (float)git[i];
    else if (i == 2048) out[O_JS] = js[0];
}

// gather rows: r<64 -> template row r; else kept search row ord[r-64]
__global__ __launch_bounds__(192)
void gather_kernel(const float* __restrict__ X1, const int* __restrict__ ord,
                   float* __restrict__ X1g)
{
    int rowid = blockIdx.x;                 // 0 .. 2*32*244-1
    int m   = rowid / (BATCH * NK);
    int rem = rowid - m * (BATCH * NK);
    int b   = rem / NK;
    int r   = rem - b * NK;
    int src = (r < LT) ? r : (LT + ord[b * 256 + (r - LT)]);
    const float4* s = (const float4*)(X1 + ((LL)m * BATCH * NTOK + b * NTOK + src) * 768);
    float4* d = (float4*)(X1g + (LL)rowid * 768);
    d[threadIdx.x] = s[threadIdx.x];
}

// =======================================================================
extern "C" void kernel_launch(void* const* d_in, const int* in_sizes, int n_in,
                              void* d_out, int out_size, void* d_ws, size_t ws_size,
                              hipStream_t stream)
{
    const float* xin_m[2] = { (const float*)d_in[0], (const float*)d_in[1] };
    const int*   git    = (const int*)d_in[2];
    const int*   gis    = (const int*)d_in[3];
    // d_in[4] mask (all False), d_in[5] template mask (all True), d_in[6] unused
    const float* js     = (const float*)d_in[7];
    const float* g1     = (const float*)d_in[8];
    const float* b1     = (const float*)d_in[9];
    const float* w_qkv  = (const float*)d_in[10];
    const float* w_proj = (const float*)d_in[11];
    const float* b_proj = (const float*)d_in[12];
    const float* g2     = (const float*)d_in[13];
    const float* b2     = (const float*)d_in[14];
    const float* w_fc1  = (const float*)d_in[15];
    const float* b_fc1  = (const float*)d_in[16];
    const float* w_fc2  = (const float*)d_in[17];
    const float* b_fc2  = (const float*)d_in[18];

    float* out = (float*)d_out;
    float* ws  = (float*)d_ws;

    float*  Xn  = ws + W_XN;
    float*  QKV = ws + W_QKV;   // also reused as H1 in MLP stage
    float*  ATT = ws + W_ATT;
    double* sc  = (double*)(ws + W_SC);
    int*    ord = (int*)(ws + W_ORD);

    // ---------------- attention stage (per modality) ----------------
    for (int m = 0; m < 2; ++m) {
        const float* xin = xin_m[m];
        float* corr = out + (m ? O_CT : O_CR);
        float* X1m  = ws + W_X1 + (LL)m * BATCH * NTOK * CDIM;

        ln_kernel<<<dim3(BATCH * NTOK), dim3(256), 0, stream>>>(xin, g1, b1, Xn);

        // QKV = Xn @ w_qkv^T   (10240 x 2304)
        gemm_f32<true><<<dim3(36, 160, 1), dim3(256), 0, stream>>>(
            Xn, w_qkv, QKV, nullptr, nullptr,
            10240, 2304, 768, 768, 768, 2304, 0,
            1, 0, 0, 0, 0, 0, 0, 0, 1.0f, 0);

        // S = Q @ K^T * 0.125  -> corrmap region (pre-softmax), batched over (b,h)
        gemm_f32<true><<<dim3(5, 5, BATCH * HEADS), dim3(256), 0, stream>>>(
            QKV, QKV + 768, corr, nullptr, nullptr,
            320, 320, 64, 2304, 2304, 320, 0,
            HEADS, 737280, 64, 737280, 64, 1228800, 102400, 0, 0.125f, 0);

        softmax_kernel<<<dim3(BATCH * HEADS * NTOK / 4), dim3(256), 0, stream>>>(corr);

        // O = A @ V  (NN), batched over (b,h) -> attn_out [10240 x 768]
        gemm_f32<false><<<dim3(1, 5, BATCH * HEADS), dim3(256), 0, stream>>>(
            corr, QKV + 1536, ATT, nullptr, nullptr,
            320, 64, 320, 320, 2304, 768, 0,
            HEADS, 1228800, 102400, 737280, 64, 245760, 64, 0, 1.0f, 0);

        // X1 = x + attn_out @ w_proj^T + b_proj
        gemm_f32<true><<<dim3(12, 160, 1), dim3(256), 0, stream>>>(
            ATT, w_proj, X1m, b_proj, xin,
            10240, 768, 768, 768, 768, 768, 768,
            1, 0, 0, 0, 0, 0, 0, 0, 1.0f, 0);
    }

    // ---------------- scoring / top-k / gather ----------------
    score_reduce<<<dim3(BATCH), dim3(256), 0, stream>>>(out + O_CR, out + O_CT, sc);
    rank_kernel<<<dim3(BATCH), dim3(256), 0, stream>>>(sc, gis, ord,
                                                       out + O_GSN, out + O_REM);
    copy_misc<<<dim3(9), dim3(256), 0, stream>>>(git, js, out);
    gather_kernel<<<dim3(2 * BATCH * NK), dim3(192), 0, stream>>>(ws + W_X1, ord, ws + W_X1G);

    // ---------------- MLP stage (per modality) ----------------
    for (int m = 0; m < 2; ++m) {
        float* X1Gm = ws + W_X1G + (LL)m * BATCH * NK * CDIM;
        float* xout = out + (m ? O_XTIR : O_XRGB);
        float* H1   = QKV;  // reuse

        ln_kernel<<<dim3(BATCH * NK), dim3(256), 0, stream>>>(X1Gm, g2, b2, Xn);

        // H1 = gelu(Xn @ w_fc1^T + b_fc1)   (7808 x 3072)
        gemm_f32<true><<<dim3(48, 122, 1), dim3(256), 0, stream>>>(
            Xn, w_fc1, H1, b_fc1, nullptr,
            7808, 3072, 768, 768, 768, 3072, 0,
            1, 0, 0, 0, 0, 0, 0, 0, 1.0f, 1);

        // x_out = X1g + H1 @ w_fc2^T + b_fc2   (7808 x 768)
        gemm_f32<true><<<dim3(12, 122, 1), dim3(256), 0, stream>>>(
            H1, w_fc2, xout, b_fc2, X1Gm,
            7808, 768, 3072, 3072, 3072, 768, 768,
            1, 0, 0, 0, 0, 0, 0, 0, 1.0f, 0);
    }
}

// Round 3
// 1972.588 us; speedup vs baseline: 2.0229x; 2.0229x over previous
//
#include <hip/hip_runtime.h>

typedef long long LL;
typedef unsigned short ushort_t;
typedef __attribute__((ext_vector_type(8))) short bfrag;    // 8 bf16 (4 VGPR)
typedef __attribute__((ext_vector_type(4))) float facc;     // MFMA accumulator
typedef __attribute__((ext_vector_type(4))) unsigned short us4;

// ---- problem constants ----
constexpr int CDIM  = 768;
constexpr int HEADS = 12;
constexpr int LT    = 64;
constexpr int LS    = 256;
constexpr int NTOK  = 320;
constexpr int BATCH = 32;
constexpr int HID   = 3072;
constexpr int LKEEP = 180;
constexpr int LREM  = 76;
constexpr int NK    = 244;

// ---- d_out element offsets (all f32) ----
constexpr LL O_XRGB = 0;
constexpr LL O_XTIR = 5996544;
constexpr LL O_GIT  = 11993088;
constexpr LL O_GSN  = 11995136;
constexpr LL O_REM  = 12000896;
constexpr LL O_CR   = 12003328;
constexpr LL O_CT   = 51324928;
constexpr LL O_JS   = 90646528;

// ---- workspace float offsets ----
constexpr LL W_X1   = 0;          // 2*32*320*768
constexpr LL W_X1G  = 15728640;   // 2*32*244*768 (Wproj_b overlays until gather)
constexpr LL W_SC   = 27721728;   // 32*256 doubles
constexpr LL W_ORD  = 27738112;   // 32*256 ints
constexpr LL W_XN   = 27746304;   // 7.86M floats (LN1 f32 / ATT_bf16 / LN2 bf16)
constexpr LL W_QKV  = 35610624;   // 23.99M floats (QKV f32 / H1 bf16)
constexpr LL W_ATT  = 59596800;   // 7.86M floats (AV out f32 / Wfc1_b+Wfc2_b)

__device__ inline ushort_t cvt_bf16(float f) {
    union { float f; unsigned u; } x; x.f = f;
    unsigned u = x.u + 0x7fffu + ((x.u >> 16) & 1u);
    return (ushort_t)(u >> 16);
}

#define GLL(gp, lp) __builtin_amdgcn_global_load_lds( \
    (const __attribute__((address_space(1))) unsigned int*)(gp), \
    (__attribute__((address_space(3))) unsigned int*)(lp), 16, 0, 0)

// =======================================================================
// LayerNorm: one block per 768-elem row. B16OUT -> write bf16 (ushort)
// =======================================================================
template<bool B16OUT>
__global__ __launch_bounds__(256)
void ln_kernel(const float* __restrict__ x, const float* __restrict__ g,
               const float* __restrict__ bta, void* __restrict__ y)
{
    LL row = blockIdx.x;
    const float* xr = x + row * 768;
    int t = threadIdx.x;
    float v0 = xr[t], v1 = xr[t + 256], v2 = xr[t + 512];
    __shared__ float red[256];
    red[t] = v0 + v1 + v2;
    __syncthreads();
    for (int s = 128; s; s >>= 1) { if (t < s) red[t] += red[t + s]; __syncthreads(); }
    float mean = red[0] / 768.0f;
    __syncthreads();
    float d0 = v0 - mean, d1 = v1 - mean, d2 = v2 - mean;
    red[t] = d0 * d0 + d1 * d1 + d2 * d2;
    __syncthreads();
    for (int s = 128; s; s >>= 1) { if (t < s) red[t] += red[t + s]; __syncthreads(); }
    float var = red[0] / 768.0f;
    float rs = 1.0f / sqrtf(var + 1e-5f);
    float o0 = d0 * rs * g[t]       + bta[t];
    float o1 = d1 * rs * g[t + 256] + bta[t + 256];
    float o2 = d2 * rs * g[t + 512] + bta[t + 512];
    if (B16OUT) {
        ushort_t* yr = (ushort_t*)y + row * 768;
        yr[t] = cvt_bf16(o0); yr[t + 256] = cvt_bf16(o1); yr[t + 512] = cvt_bf16(o2);
    } else {
        float* yr = (float*)y + row * 768;
        yr[t] = o0; yr[t + 256] = o1; yr[t + 512] = o2;
    }
}

// =======================================================================
// Tiled f32 GEMM (unchanged from passing round) — used for the
// ordering-critical path: QKV, QK^T, AV.
// =======================================================================
template<bool TRANSB>
__global__ __launch_bounds__(256)
void gemm_f32(const float* __restrict__ A, const float* __restrict__ B,
              float* __restrict__ C, const float* __restrict__ bias,
              const float* __restrict__ res,
              int M, int N, int K, int lda, int ldb, int ldc, int ldres,
              int divH, LL sA1, LL sA2, LL sB1, LL sB2, LL sC1, LL sC2, LL sRes1,
              float scale, int act)
{
    int z = blockIdx.z;
    int zb = z / divH, zh = z - zb * divH;
    A += zb * sA1 + zh * sA2;
    B += zb * sB1 + zh * sB2;
    C += zb * sC1 + zh * sC2;
    if (res) res += zb * sRes1;

    __shared__ float As[16][68];
    __shared__ float Bs[16][68];
    const int t  = threadIdx.x;
    const int tx = t & 15, ty = t >> 4;
    const int bm = blockIdx.y * 64, bn = blockIdx.x * 64;

    const int lr = t >> 2;
    const int lk = (t & 3) * 4;
    const int nr = t >> 4;
    const int nc = (t & 15) * 4;

    float acc[4][4] = {};

    for (int k0 = 0; k0 < K; k0 += 16) {
        float4 av = *(const float4*)(A + (LL)(bm + lr) * lda + (k0 + lk));
        float4 bv;
        if (TRANSB) bv = *(const float4*)(B + (LL)(bn + lr) * ldb + (k0 + lk));
        else        bv = *(const float4*)(B + (LL)(k0 + nr) * ldb + (bn + nc));
        __syncthreads();
        As[lk + 0][lr] = av.x; As[lk + 1][lr] = av.y;
        As[lk + 2][lr] = av.z; As[lk + 3][lr] = av.w;
        if (TRANSB) {
            Bs[lk + 0][lr] = bv.x; Bs[lk + 1][lr] = bv.y;
            Bs[lk + 2][lr] = bv.z; Bs[lk + 3][lr] = bv.w;
        } else {
            *(float4*)&Bs[nr][nc] = bv;
        }
        __syncthreads();
        #pragma unroll
        for (int k = 0; k < 16; ++k) {
            float4 af = *(const float4*)&As[k][ty * 4];
            float4 bf = *(const float4*)&Bs[k][tx * 4];
            float ar[4] = {af.x, af.y, af.z, af.w};
            float br[4] = {bf.x, bf.y, bf.z, bf.w};
            #pragma unroll
            for (int i = 0; i < 4; ++i)
                #pragma unroll
                for (int j = 0; j < 4; ++j)
                    acc[i][j] = fmaf(ar[i], br[j], acc[i][j]);
        }
    }

    #pragma unroll
    for (int i = 0; i < 4; ++i) {
        int gm = bm + ty * 4 + i;
        #pragma unroll
        for (int j = 0; j < 4; ++j) {
            int gn = bn + tx * 4 + j;
            float v = acc[i][j] * scale;
            if (bias) v += bias[gn];
            if (act)  v = 0.5f * v * (erff(v * 0.70710678118654752f) + 1.0f);
            if (res)  v += res[(LL)gm * ldres + gn];
            C[(LL)gm * ldc + gn] = v;
        }
    }
}

// =======================================================================
// bf16 MFMA GEMM, 128x128 tile, BK=32, 4 waves (m97 structure).
// A[M,K] bf16 row-major, B[N,K] bf16 row-major (i.e. X @ W^T).
// EPI=1: bias+GELU -> bf16 out.  EPI=2: bias+residual -> f32 out.
// Requires M%128==0, N%128==0, K%32==0.
// =======================================================================
template<int EPI>
__global__ __launch_bounds__(256)
void gemm_mfma(const ushort_t* __restrict__ A, const ushort_t* __restrict__ B,
               void* __restrict__ Cv, const float* __restrict__ bias,
               const float* __restrict__ res,
               int K, int lda, int ldb, int ldc, int ldres)
{
    __shared__ ushort_t As[4096];   // 128 rows x 32 k (bf16)
    __shared__ ushort_t Bs[4096];
    const int t = threadIdx.x;
    const int wave = t >> 6, lane = t & 63;
    const int wr = wave >> 1, wc = wave & 1;
    const LL bm = (LL)blockIdx.y * 128, bn = (LL)blockIdx.x * 128;

    facc acc[4][4];
    #pragma unroll
    for (int i = 0; i < 4; ++i)
        #pragma unroll
        for (int j = 0; j < 4; ++j) acc[i][j] = (facc)(0.0f);

    const int lr = lane & 15, lh = lane >> 4;
    // staging map: lane covers tile elems wave*512 + lane*8 (row = wave*16 + lane/4)
    const ushort_t* gA = A + (bm + wave * 16 + (lane >> 2)) * lda + (lane & 3) * 8;
    const ushort_t* gB = B + (bn + wave * 16 + (lane >> 2)) * ldb + (lane & 3) * 8;
    const LL a64 = (LL)64 * lda, b64 = (LL)64 * ldb;

    for (int k0 = 0; k0 < K; k0 += 32) {
        __syncthreads();                       // LDS free (prev reads drained)
        GLL(gA + k0,        &As[wave * 512]);
        GLL(gA + k0 + a64,  &As[2048 + wave * 512]);
        GLL(gB + k0,        &Bs[wave * 512]);
        GLL(gB + k0 + b64,  &Bs[2048 + wave * 512]);
        __syncthreads();                       // compiler drains vmcnt before barrier
        bfrag a[4], b[4];
        #pragma unroll
        for (int m = 0; m < 4; ++m)
            a[m] = *(const bfrag*)&As[(wr * 64 + m * 16 + lr) * 32 + lh * 8];
        #pragma unroll
        for (int n = 0; n < 4; ++n)
            b[n] = *(const bfrag*)&Bs[(wc * 64 + n * 16 + lr) * 32 + lh * 8];
        #pragma unroll
        for (int m = 0; m < 4; ++m)
            #pragma unroll
            for (int n = 0; n < 4; ++n)
                acc[m][n] = __builtin_amdgcn_mfma_f32_16x16x32_bf16(a[m], b[n], acc[m][n], 0, 0, 0);
    }

    #pragma unroll
    for (int m = 0; m < 4; ++m) {
        #pragma unroll
        for (int n = 0; n < 4; ++n) {
            #pragma unroll
            for (int j = 0; j < 4; ++j) {
                LL r = bm + wr * 64 + m * 16 + lh * 4 + j;
                LL c = bn + wc * 64 + n * 16 + lr;
                float v = acc[m][n][j] + bias[c];
                if (EPI == 1) {
                    v = 0.5f * v * (erff(v * 0.70710678118654752f) + 1.0f);
                    ((ushort_t*)Cv)[r * ldc + c] = cvt_bf16(v);
                } else {
                    v += res[r * ldres + c];
                    ((float*)Cv)[r * ldc + c] = v;
                }
            }
        }
    }
}

// =======================================================================
// flat f32 -> bf16 convert (n % 4 == 0)
// =======================================================================
__global__ __launch_bounds__(256)
void f32_to_bf16(const float* __restrict__ in, ushort_t* __restrict__ out, int n)
{
    int i = (blockIdx.x * 256 + threadIdx.x) * 4;
    if (i >= n) return;
    float4 v = *(const float4*)(in + i);
    us4 o;
    o[0] = cvt_bf16(v.x); o[1] = cvt_bf16(v.y);
    o[2] = cvt_bf16(v.z); o[3] = cvt_bf16(v.w);
    *(us4*)(out + i) = o;
}

// =======================================================================
// In-place row softmax over 320 elems
// =======================================================================
__global__ __launch_bounds__(256)
void softmax_kernel(float* __restrict__ p)
{
    LL row = (LL)blockIdx.x * 4 + (threadIdx.x >> 6);
    int lane = threadIdx.x & 63;
    float* pr = p + row * 320;
    float v[5];
    #pragma unroll
    for (int i = 0; i < 5; ++i) v[i] = pr[lane + i * 64];
    float mx = v[0];
    #pragma unroll
    for (int i = 1; i < 5; ++i) mx = fmaxf(mx, v[i]);
    for (int o = 32; o; o >>= 1) mx = fmaxf(mx, __shfl_down(mx, o, 64));
    mx = __shfl(mx, 0, 64);
    float e[5], s = 0.0f;
    #pragma unroll
    for (int i = 0; i < 5; ++i) { e[i] = expf(v[i] - mx); s += e[i]; }
    for (int o = 32; o; o >>= 1) s += __shfl_down(s, o, 64);
    s = __shfl(s, 0, 64);
    #pragma unroll
    for (int i = 0; i < 5; ++i) pr[lane + i * 64] = e[i] / s;
}

// =======================================================================
// f64 score reduce + stable rank (ordering-critical, unchanged)
// =======================================================================
__global__ __launch_bounds__(256)
void score_reduce(const float* __restrict__ c0, const float* __restrict__ c1,
                  double* __restrict__ scores)
{
    int b = blockIdx.x, j = threadIdx.x;
    const float* p0 = c0 + (LL)b * HEADS * NTOK * NTOK + LT + j;
    const float* p1 = c1 + (LL)b * HEADS * NTOK * NTOK + LT + j;
    double acc = 0.0;
    for (int h = 0; h < HEADS; ++h) {
        const float* q0 = p0 + (LL)h * NTOK * NTOK;
        const float* q1 = p1 + (LL)h * NTOK * NTOK;
        double ah = 0.0;
        for (int tq = 0; tq < LT; ++tq)
            ah += (double)q0[tq * NTOK] + (double)q1[tq * NTOK];
        acc += ah / 64.0;
    }
    scores[b * 256 + j] = acc / 12.0;
}

__global__ __launch_bounds__(256)
void rank_kernel(const double* __restrict__ scores, const int* __restrict__ gis,
                 int* __restrict__ ord, float* __restrict__ onew, float* __restrict__ orem)
{
    int b = blockIdx.x, j = threadIdx.x;
    __shared__ double s[256];
    s[j] = scores[b * 256 + j];
    __syncthreads();
    double sj = s[j];
    int r = 0;
    for (int i = 0; i < 256; ++i) {
        double si = s[i];
        r += (si > sj) || (si == sj && i < j);
    }
    ord[b * 256 + r] = j;
    float gv = (float)gis[b * 256 + j];
    if (r < LKEEP) onew[b * LKEEP + r] = gv;
    else           orem[b * LREM + (r - LKEEP)] = gv;
}

__global__ void copy_misc(const int* __restrict__ git, const float* __restrict__ js,
                          float* __restrict__ out)
{
    int i = blockIdx.x * 256 + threadIdx.x;
    if (i < 2048)      out[O_GIT + i] = (float)git[i];
    else if (i == 2048) out[O_JS] = js[0];
}

__global__ __launch_bounds__(192)
void gather_kernel(const float* __restrict__ X1, const int* __restrict__ ord,
                   float* __restrict__ X1g)
{
    int rowid = blockIdx.x;
    int m   = rowid / (BATCH * NK);
    int rem = rowid - m * (BATCH * NK);
    int b   = rem / NK;
    int r   = rem - b * NK;
    int src = (r < LT) ? r : (LT + ord[b * 256 + (r - LT)]);
    const float4* s = (const float4*)(X1 + ((LL)m * BATCH * NTOK + b * NTOK + src) * 768);
    float4* d = (float4*)(X1g + (LL)rowid * 768);
    d[threadIdx.x] = s[threadIdx.x];
}

// =======================================================================
extern "C" void kernel_launch(void* const* d_in, const int* in_sizes, int n_in,
                              void* d_out, int out_size, void* d_ws, size_t ws_size,
                              hipStream_t stream)
{
    const float* xin_m[2] = { (const float*)d_in[0], (const float*)d_in[1] };
    const int*   git    = (const int*)d_in[2];
    const int*   gis    = (const int*)d_in[3];
    const float* js     = (const float*)d_in[7];
    const float* g1     = (const float*)d_in[8];
    const float* b1     = (const float*)d_in[9];
    const float* w_qkv  = (const float*)d_in[10];
    const float* w_proj = (const float*)d_in[11];
    const float* b_proj = (const float*)d_in[12];
    const float* g2     = (const float*)d_in[13];
    const float* b2     = (const float*)d_in[14];
    const float* w_fc1  = (const float*)d_in[15];
    const float* b_fc1  = (const float*)d_in[16];
    const float* w_fc2  = (const float*)d_in[17];
    const float* b_fc2  = (const float*)d_in[18];

    float* out = (float*)d_out;
    float* ws  = (float*)d_ws;

    float*   Xn   = ws + W_XN;
    float*   QKV  = ws + W_QKV;
    float*   ATT  = ws + W_ATT;
    double*  sc   = (double*)(ws + W_SC);
    int*     ord  = (int*)(ws + W_ORD);

    // bf16 overlays (regions dead at time of use)
    ushort_t* ATTb   = (ushort_t*)(ws + W_XN);              // attention stage, after QKV
    ushort_t* WPROJb = (ushort_t*)(ws + W_X1G);             // until gather
    ushort_t* WFC1b  = (ushort_t*)(ws + W_ATT);             // MLP stage
    ushort_t* WFC2b  = (ushort_t*)(ws + W_ATT + 1179648);
    ushort_t* XN2b   = (ushort_t*)(ws + W_XN);              // MLP stage
    ushort_t* H1b    = (ushort_t*)(ws + W_QKV);             // MLP stage

    // convert w_proj once (589824 elems)
    f32_to_bf16<<<dim3(576), dim3(256), 0, stream>>>(w_proj, WPROJb, 589824);

    // ---------------- attention stage (per modality) ----------------
    for (int m = 0; m < 2; ++m) {
        const float* xin = xin_m[m];
        float* corr = out + (m ? O_CT : O_CR);
        float* X1m  = ws + W_X1 + (LL)m * BATCH * NTOK * CDIM;

        ln_kernel<false><<<dim3(BATCH * NTOK), dim3(256), 0, stream>>>(xin, g1, b1, Xn);

        // QKV = Xn @ w_qkv^T  (f32 — ordering-critical)
        gemm_f32<true><<<dim3(36, 160, 1), dim3(256), 0, stream>>>(
            Xn, w_qkv, QKV, nullptr, nullptr,
            10240, 2304, 768, 768, 768, 2304, 0,
            1, 0, 0, 0, 0, 0, 0, 0, 1.0f, 0);

        // S = Q @ K^T * 0.125 (f32 — ordering-critical)
        gemm_f32<true><<<dim3(5, 5, BATCH * HEADS), dim3(256), 0, stream>>>(
            QKV, QKV + 768, corr, nullptr, nullptr,
            320, 320, 64, 2304, 2304, 320, 0,
            HEADS, 737280, 64, 737280, 64, 1228800, 102400, 0, 0.125f, 0);

        softmax_kernel<<<dim3(BATCH * HEADS * NTOK / 4), dim3(256), 0, stream>>>(corr);

        // O = A @ V (f32)
        gemm_f32<false><<<dim3(1, 5, BATCH * HEADS), dim3(256), 0, stream>>>(
            corr, QKV + 1536, ATT, nullptr, nullptr,
            320, 64, 320, 320, 2304, 768, 0,
            HEADS, 1228800, 102400, 737280, 64, 245760, 64, 0, 1.0f, 0);

        // ATT -> bf16 (Xn region is dead now)
        f32_to_bf16<<<dim3(7680), dim3(256), 0, stream>>>(ATT, ATTb, 7864320);

        // X1 = xin + ATTb @ WPROJb^T + b_proj  (bf16 MFMA)
        gemm_mfma<2><<<dim3(6, 80), dim3(256), 0, stream>>>(
            ATTb, WPROJb, X1m, b_proj, xin, 768, 768, 768, 768, 768);
    }

    // ---------------- scoring / top-k / gather ----------------
    score_reduce<<<dim3(BATCH), dim3(256), 0, stream>>>(out + O_CR, out + O_CT, sc);
    rank_kernel<<<dim3(BATCH), dim3(256), 0, stream>>>(sc, gis, ord,
                                                       out + O_GSN, out + O_REM);
    copy_misc<<<dim3(9), dim3(256), 0, stream>>>(git, js, out);
    gather_kernel<<<dim3(2 * BATCH * NK), dim3(192), 0, stream>>>(ws + W_X1, ord, ws + W_X1G);

    // convert MLP weights (ATT region dead now)
    f32_to_bf16<<<dim3(2304), dim3(256), 0, stream>>>(w_fc1, WFC1b, 2359296);
    f32_to_bf16<<<dim3(2304), dim3(256), 0, stream>>>(w_fc2, WFC2b, 2359296);

    // ---------------- MLP stage (per modality) ----------------
    for (int m = 0; m < 2; ++m) {
        float* X1Gm = ws + W_X1G + (LL)m * BATCH * NK * CDIM;
        float* xout = out + (m ? O_XTIR : O_XRGB);

        ln_kernel<true><<<dim3(BATCH * NK), dim3(256), 0, stream>>>(X1Gm, g2, b2, XN2b);

        // H1 = gelu(XN2b @ WFC1b^T + b_fc1) -> bf16  (7808 x 3072)
        gemm_mfma<1><<<dim3(24, 61), dim3(256), 0, stream>>>(
            XN2b, WFC1b, H1b, b_fc1, nullptr, 768, 768, 768, 3072, 0);

        // x_out = X1g + H1b @ WFC2b^T + b_fc2  (7808 x 768)
        gemm_mfma<2><<<dim3(6, 61), dim3(256), 0, stream>>>(
            H1b, WFC2b, xout, b_fc2, X1Gm, 3072, 3072, 3072, 768, 768);
    }
}

// Round 4
// 1224.857 us; speedup vs baseline: 3.2578x; 1.6105x over previous
//
#include <hip/hip_runtime.h>

typedef long long LL;
typedef unsigned short ushort_t;
typedef __attribute__((ext_vector_type(8))) short bfrag;      // 8 bf16
typedef __attribute__((ext_vector_type(8))) _Float16 hfrag;   // 8 f16
typedef __attribute__((ext_vector_type(4))) float facc;
typedef __attribute__((ext_vector_type(4))) unsigned short us4;

// ---- problem constants ----
constexpr int CDIM  = 768;
constexpr int HEADS = 12;
constexpr int LT    = 64;
constexpr int LS    = 256;
constexpr int NTOK  = 320;
constexpr int BATCH = 32;
constexpr int HID   = 3072;
constexpr int LKEEP = 180;
constexpr int LREM  = 76;
constexpr int NK    = 244;

// ---- d_out element offsets (all f32) ----
constexpr LL O_XRGB = 0;
constexpr LL O_XTIR = 5996544;
constexpr LL O_GIT  = 11993088;
constexpr LL O_GSN  = 11995136;
constexpr LL O_REM  = 12000896;
constexpr LL O_CR   = 12003328;
constexpr LL O_CT   = 51324928;
constexpr LL O_JS   = 90646528;

// ---- workspace float offsets ----
constexpr LL W_X1   = 0;          // 2*32*320*768
constexpr LL W_X1G  = 15728640;   // 2*32*244*768 (Wproj_b overlays until gather)
constexpr LL W_SC   = 27721728;   // 32*256 doubles
constexpr LL W_ORD  = 27738112;   // 32*256 ints
constexpr LL W_XN   = 27746304;   // 31.4MB: LN1 f16 hi+lo / ATTb / LN2 bf16
constexpr LL W_QKV  = 35610624;   // QKV f32 / H1 bf16
constexpr LL W_ATT  = 59596800;   // Wqkv f16 hi+lo / Wfc1_b+Wfc2_b

__device__ inline ushort_t cvt_bf16(float f) {
    union { float f; unsigned u; } x; x.f = f;
    unsigned u = x.u + 0x7fffu + ((x.u >> 16) & 1u);
    return (ushort_t)(u >> 16);
}
union h16u { _Float16 h; ushort_t u; };

#define GLL(gp, lp) __builtin_amdgcn_global_load_lds( \
    (const __attribute__((address_space(1))) unsigned int*)(gp), \
    (__attribute__((address_space(3))) unsigned int*)(lp), 16, 0, 0)

// =======================================================================
// LayerNorm -> f32 or bf16 (as before)
// =======================================================================
template<bool B16OUT>
__global__ __launch_bounds__(256)
void ln_kernel(const float* __restrict__ x, const float* __restrict__ g,
               const float* __restrict__ bta, void* __restrict__ y)
{
    LL row = blockIdx.x;
    const float* xr = x + row * 768;
    int t = threadIdx.x;
    float v0 = xr[t], v1 = xr[t + 256], v2 = xr[t + 512];
    __shared__ float red[256];
    red[t] = v0 + v1 + v2;
    __syncthreads();
    for (int s = 128; s; s >>= 1) { if (t < s) red[t] += red[t + s]; __syncthreads(); }
    float mean = red[0] / 768.0f;
    __syncthreads();
    float d0 = v0 - mean, d1 = v1 - mean, d2 = v2 - mean;
    red[t] = d0 * d0 + d1 * d1 + d2 * d2;
    __syncthreads();
    for (int s = 128; s; s >>= 1) { if (t < s) red[t] += red[t + s]; __syncthreads(); }
    float var = red[0] / 768.0f;
    float rs = 1.0f / sqrtf(var + 1e-5f);
    float o0 = d0 * rs * g[t]       + bta[t];
    float o1 = d1 * rs * g[t + 256] + bta[t + 256];
    float o2 = d2 * rs * g[t + 512] + bta[t + 512];
    if (B16OUT) {
        ushort_t* yr = (ushort_t*)y + row * 768;
        yr[t] = cvt_bf16(o0); yr[t + 256] = cvt_bf16(o1); yr[t + 512] = cvt_bf16(o2);
    } else {
        float* yr = (float*)y + row * 768;
        yr[t] = o0; yr[t + 256] = o1; yr[t + 512] = o2;
    }
}

// =======================================================================
// LayerNorm -> f16 hi/lo split (for the split-f16 MFMA QKV GEMM)
// =======================================================================
__global__ __launch_bounds__(256)
void ln_f16x2(const float* __restrict__ x, const float* __restrict__ g,
              const float* __restrict__ bta,
              ushort_t* __restrict__ yh, ushort_t* __restrict__ yl)
{
    LL row = blockIdx.x;
    const float* xr = x + row * 768;
    int t = threadIdx.x;
    float v0 = xr[t], v1 = xr[t + 256], v2 = xr[t + 512];
    __shared__ float red[256];
    red[t] = v0 + v1 + v2;
    __syncthreads();
    for (int s = 128; s; s >>= 1) { if (t < s) red[t] += red[t + s]; __syncthreads(); }
    float mean = red[0] / 768.0f;
    __syncthreads();
    float d0 = v0 - mean, d1 = v1 - mean, d2 = v2 - mean;
    red[t] = d0 * d0 + d1 * d1 + d2 * d2;
    __syncthreads();
    for (int s = 128; s; s >>= 1) { if (t < s) red[t] += red[t + s]; __syncthreads(); }
    float var = red[0] / 768.0f;
    float rs = 1.0f / sqrtf(var + 1e-5f);
    #pragma unroll
    for (int c = 0; c < 3; ++c) {
        float d = (c == 0 ? d0 : c == 1 ? d1 : d2);
        int idx = t + c * 256;
        float o = d * rs * g[idx] + bta[idx];
        h16u hi, lo;
        hi.h = (_Float16)o;
        lo.h = (_Float16)(o - (float)hi.h);
        yh[row * 768 + idx] = hi.u;
        yl[row * 768 + idx] = lo.u;
    }
}

// f32 -> f16 hi/lo split, flat (n % 4 == 0)
__global__ __launch_bounds__(256)
void cvt_f16x2(const float* __restrict__ in, ushort_t* __restrict__ oh,
               ushort_t* __restrict__ ol, int n)
{
    int i = (blockIdx.x * 256 + threadIdx.x) * 4;
    if (i >= n) return;
    float4 v = *(const float4*)(in + i);
    us4 h, l;
    #pragma unroll
    for (int j = 0; j < 4; ++j) {
        float f = (j == 0 ? v.x : j == 1 ? v.y : j == 2 ? v.z : v.w);
        h16u hh, ll;
        hh.h = (_Float16)f;
        ll.h = (_Float16)(f - (float)hh.h);
        h[j] = hh.u; l[j] = ll.u;
    }
    *(us4*)(oh + i) = h;
    *(us4*)(ol + i) = l;
}

// =======================================================================
// Split-f16 3-pass MFMA GEMM (near-f32 accuracy): C = (Ah+Al)(Bh+Bl)^T
// 128x128 tile, BK=32, 4 waves. A[M,K], B[N,K] row-major f16 pairs.
// C f32 [M x ldc]. Requires M%128==0, N%128==0, K%32==0.
// =======================================================================
__global__ __launch_bounds__(256)
void gemm_f16x2(const ushort_t* __restrict__ Ah, const ushort_t* __restrict__ Al,
                const ushort_t* __restrict__ Bh, const ushort_t* __restrict__ Bl,
                float* __restrict__ C, int K, int lda, int ldb, int ldc)
{
    __shared__ ushort_t Ahs[4096], Als[4096], Bhs[4096], Bls[4096];
    const int t = threadIdx.x;
    const int wave = t >> 6, lane = t & 63;
    const int wr = wave >> 1, wc = wave & 1;
    const int lr = lane & 15, lh = lane >> 4;
    const LL bm = (LL)blockIdx.y * 128, bn = (LL)blockIdx.x * 128;

    facc acc[4][4];
    #pragma unroll
    for (int i = 0; i < 4; ++i)
        #pragma unroll
        for (int j = 0; j < 4; ++j) acc[i][j] = (facc)(0.0f);

    const LL soff = (bm + wave * 16 + (lane >> 2)) * (LL)lda + (lane & 3) * 8;
    const LL boff = (bn + wave * 16 + (lane >> 2)) * (LL)ldb + (lane & 3) * 8;
    const LL a64 = (LL)64 * lda, b64 = (LL)64 * ldb;

    for (int k0 = 0; k0 < K; k0 += 32) {
        __syncthreads();
        GLL(Ah + soff + k0,       &Ahs[wave * 512]);
        GLL(Ah + soff + k0 + a64, &Ahs[2048 + wave * 512]);
        GLL(Al + soff + k0,       &Als[wave * 512]);
        GLL(Al + soff + k0 + a64, &Als[2048 + wave * 512]);
        GLL(Bh + boff + k0,       &Bhs[wave * 512]);
        GLL(Bh + boff + k0 + b64, &Bhs[2048 + wave * 512]);
        GLL(Bl + boff + k0,       &Bls[wave * 512]);
        GLL(Bl + boff + k0 + b64, &Bls[2048 + wave * 512]);
        __syncthreads();
        hfrag ah[4], al[4], bh[4], bl[4];
        #pragma unroll
        for (int m = 0; m < 4; ++m) {
            int off = (wr * 64 + m * 16 + lr) * 32 + lh * 8;
            ah[m] = *(const hfrag*)&Ahs[off];
            al[m] = *(const hfrag*)&Als[off];
        }
        #pragma unroll
        for (int n = 0; n < 4; ++n) {
            int off = (wc * 64 + n * 16 + lr) * 32 + lh * 8;
            bh[n] = *(const hfrag*)&Bhs[off];
            bl[n] = *(const hfrag*)&Bls[off];
        }
        #pragma unroll
        for (int m = 0; m < 4; ++m)
            #pragma unroll
            for (int n = 0; n < 4; ++n) {
                acc[m][n] = __builtin_amdgcn_mfma_f32_16x16x32_f16(al[m], bh[n], acc[m][n], 0, 0, 0);
                acc[m][n] = __builtin_amdgcn_mfma_f32_16x16x32_f16(ah[m], bl[n], acc[m][n], 0, 0, 0);
                acc[m][n] = __builtin_amdgcn_mfma_f32_16x16x32_f16(ah[m], bh[n], acc[m][n], 0, 0, 0);
            }
    }

    #pragma unroll
    for (int m = 0; m < 4; ++m)
        #pragma unroll
        for (int n = 0; n < 4; ++n)
            #pragma unroll
            for (int j = 0; j < 4; ++j) {
                LL r = bm + wr * 64 + m * 16 + lh * 4 + j;
                LL c = bn + wc * 64 + n * 16 + lr;
                C[r * ldc + c] = acc[m][n][j];
            }
}

// =======================================================================
// Tiled f32 GEMM (ordering-critical path: QK^T, AV). OUTBF: bf16 output.
// =======================================================================
template<bool TRANSB, bool OUTBF>
__global__ __launch_bounds__(256)
void gemm_f32(const float* __restrict__ A, const float* __restrict__ B,
              void* __restrict__ Cv, const float* __restrict__ bias,
              const float* __restrict__ res,
              int M, int N, int K, int lda, int ldb, int ldc, int ldres,
              int divH, LL sA1, LL sA2, LL sB1, LL sB2, LL sC1, LL sC2, LL sRes1,
              float scale, int act)
{
    int z = blockIdx.z;
    int zb = z / divH, zh = z - zb * divH;
    A += zb * sA1 + zh * sA2;
    B += zb * sB1 + zh * sB2;
    if (res) res += zb * sRes1;
    LL coff = zb * sC1 + zh * sC2;

    __shared__ float As[16][68];
    __shared__ float Bs[16][68];
    const int t  = threadIdx.x;
    const int tx = t & 15, ty = t >> 4;
    const int bm = blockIdx.y * 64, bn = blockIdx.x * 64;

    const int lr = t >> 2;
    const int lk = (t & 3) * 4;
    const int nr = t >> 4;
    const int nc = (t & 15) * 4;

    float acc[4][4] = {};

    for (int k0 = 0; k0 < K; k0 += 16) {
        float4 av = *(const float4*)(A + (LL)(bm + lr) * lda + (k0 + lk));
        float4 bv;
        if (TRANSB) bv = *(const float4*)(B + (LL)(bn + lr) * ldb + (k0 + lk));
        else        bv = *(const float4*)(B + (LL)(k0 + nr) * ldb + (bn + nc));
        __syncthreads();
        As[lk + 0][lr] = av.x; As[lk + 1][lr] = av.y;
        As[lk + 2][lr] = av.z; As[lk + 3][lr] = av.w;
        if (TRANSB) {
            Bs[lk + 0][lr] = bv.x; Bs[lk + 1][lr] = bv.y;
            Bs[lk + 2][lr] = bv.z; Bs[lk + 3][lr] = bv.w;
        } else {
            *(float4*)&Bs[nr][nc] = bv;
        }
        __syncthreads();
        #pragma unroll
        for (int k = 0; k < 16; ++k) {
            float4 af = *(const float4*)&As[k][ty * 4];
            float4 bf = *(const float4*)&Bs[k][tx * 4];
            float ar[4] = {af.x, af.y, af.z, af.w};
            float br[4] = {bf.x, bf.y, bf.z, bf.w};
            #pragma unroll
            for (int i = 0; i < 4; ++i)
                #pragma unroll
                for (int j = 0; j < 4; ++j)
                    acc[i][j] = fmaf(ar[i], br[j], acc[i][j]);
        }
    }

    #pragma unroll
    for (int i = 0; i < 4; ++i) {
        int gm = bm + ty * 4 + i;
        #pragma unroll
        for (int j = 0; j < 4; ++j) {
            int gn = bn + tx * 4 + j;
            float v = acc[i][j] * scale;
            if (bias) v += bias[gn];
            if (act)  v = 0.5f * v * (erff(v * 0.70710678118654752f) + 1.0f);
            if (res)  v += res[(LL)gm * ldres + gn];
            if (OUTBF) ((ushort_t*)Cv)[coff + (LL)gm * ldc + gn] = cvt_bf16(v);
            else       ((float*)Cv)[coff + (LL)gm * ldc + gn] = v;
        }
    }
}

// =======================================================================
// bf16 MFMA GEMM (proj / fc1 / fc2) — unchanged from round 3
// =======================================================================
template<int EPI>
__global__ __launch_bounds__(256)
void gemm_mfma(const ushort_t* __restrict__ A, const ushort_t* __restrict__ B,
               void* __restrict__ Cv, const float* __restrict__ bias,
               const float* __restrict__ res,
               int K, int lda, int ldb, int ldc, int ldres)
{
    __shared__ ushort_t As[4096];
    __shared__ ushort_t Bs[4096];
    const int t = threadIdx.x;
    const int wave = t >> 6, lane = t & 63;
    const int wr = wave >> 1, wc = wave & 1;
    const LL bm = (LL)blockIdx.y * 128, bn = (LL)blockIdx.x * 128;

    facc acc[4][4];
    #pragma unroll
    for (int i = 0; i < 4; ++i)
        #pragma unroll
        for (int j = 0; j < 4; ++j) acc[i][j] = (facc)(0.0f);

    const int lr = lane & 15, lh = lane >> 4;
    const ushort_t* gA = A + (bm + wave * 16 + (lane >> 2)) * lda + (lane & 3) * 8;
    const ushort_t* gB = B + (bn + wave * 16 + (lane >> 2)) * ldb + (lane & 3) * 8;
    const LL a64 = (LL)64 * lda, b64 = (LL)64 * ldb;

    for (int k0 = 0; k0 < K; k0 += 32) {
        __syncthreads();
        GLL(gA + k0,        &As[wave * 512]);
        GLL(gA + k0 + a64,  &As[2048 + wave * 512]);
        GLL(gB + k0,        &Bs[wave * 512]);
        GLL(gB + k0 + b64,  &Bs[2048 + wave * 512]);
        __syncthreads();
        bfrag a[4], b[4];
        #pragma unroll
        for (int m = 0; m < 4; ++m)
            a[m] = *(const bfrag*)&As[(wr * 64 + m * 16 + lr) * 32 + lh * 8];
        #pragma unroll
        for (int n = 0; n < 4; ++n)
            b[n] = *(const bfrag*)&Bs[(wc * 64 + n * 16 + lr) * 32 + lh * 8];
        #pragma unroll
        for (int m = 0; m < 4; ++m)
            #pragma unroll
            for (int n = 0; n < 4; ++n)
                acc[m][n] = __builtin_amdgcn_mfma_f32_16x16x32_bf16(a[m], b[n], acc[m][n], 0, 0, 0);
    }

    #pragma unroll
    for (int m = 0; m < 4; ++m) {
        #pragma unroll
        for (int n = 0; n < 4; ++n) {
            #pragma unroll
            for (int j = 0; j < 4; ++j) {
                LL r = bm + wr * 64 + m * 16 + lh * 4 + j;
                LL c = bn + wc * 64 + n * 16 + lr;
                float v = acc[m][n][j] + bias[c];
                if (EPI == 1) {
                    v = 0.5f * v * (erff(v * 0.70710678118654752f) + 1.0f);
                    ((ushort_t*)Cv)[r * ldc + c] = cvt_bf16(v);
                } else {
                    v += res[r * ldres + c];
                    ((float*)Cv)[r * ldc + c] = v;
                }
            }
        }
    }
}

__global__ __launch_bounds__(256)
void f32_to_bf16(const float* __restrict__ in, ushort_t* __restrict__ out, int n)
{
    int i = (blockIdx.x * 256 + threadIdx.x) * 4;
    if (i >= n) return;
    float4 v = *(const float4*)(in + i);
    us4 o;
    o[0] = cvt_bf16(v.x); o[1] = cvt_bf16(v.y);
    o[2] = cvt_bf16(v.z); o[3] = cvt_bf16(v.w);
    *(us4*)(out + i) = o;
}

// =======================================================================
// In-place row softmax over 320 elems
// =======================================================================
__global__ __launch_bounds__(256)
void softmax_kernel(float* __restrict__ p)
{
    LL row = (LL)blockIdx.x * 4 + (threadIdx.x >> 6);
    int lane = threadIdx.x & 63;
    float* pr = p + row * 320;
    float v[5];
    #pragma unroll
    for (int i = 0; i < 5; ++i) v[i] = pr[lane + i * 64];
    float mx = v[0];
    #pragma unroll
    for (int i = 1; i < 5; ++i) mx = fmaxf(mx, v[i]);
    for (int o = 32; o; o >>= 1) mx = fmaxf(mx, __shfl_down(mx, o, 64));
    mx = __shfl(mx, 0, 64);
    float e[5], s = 0.0f;
    #pragma unroll
    for (int i = 0; i < 5; ++i) { e[i] = expf(v[i] - mx); s += e[i]; }
    for (int o = 32; o; o >>= 1) s += __shfl_down(s, o, 64);
    s = __shfl(s, 0, 64);
    #pragma unroll
    for (int i = 0; i < 5; ++i) pr[lane + i * 64] = e[i] / s;
}

// =======================================================================
// f64 score reduce + stable rank (ordering-critical, unchanged)
// =======================================================================
__global__ __launch_bounds__(256)
void score_reduce(const float* __restrict__ c0, const float* __restrict__ c1,
                  double* __restrict__ scores)
{
    int b = blockIdx.x, j = threadIdx.x;
    const float* p0 = c0 + (LL)b * HEADS * NTOK * NTOK + LT + j;
    const float* p1 = c1 + (LL)b * HEADS * NTOK * NTOK + LT + j;
    double acc = 0.0;
    for (int h = 0; h < HEADS; ++h) {
        const float* q0 = p0 + (LL)h * NTOK * NTOK;
        const float* q1 = p1 + (LL)h * NTOK * NTOK;
        double ah = 0.0;
        for (int tq = 0; tq < LT; ++tq)
            ah += (double)q0[tq * NTOK] + (double)q1[tq * NTOK];
        acc += ah / 64.0;
    }
    scores[b * 256 + j] = acc / 12.0;
}

__global__ __launch_bounds__(256)
void rank_kernel(const double* __restrict__ scores, const int* __restrict__ gis,
                 int* __restrict__ ord, float* __restrict__ onew, float* __restrict__ orem)
{
    int b = blockIdx.x, j = threadIdx.x;
    __shared__ double s[256];
    s[j] = scores[b * 256 + j];
    __syncthreads();
    double sj = s[j];
    int r = 0;
    for (int i = 0; i < 256; ++i) {
        double si = s[i];
        r += (si > sj) || (si == sj && i < j);
    }
    ord[b * 256 + r] = j;
    float gv = (float)gis[b * 256 + j];
    if (r < LKEEP) onew[b * LKEEP + r] = gv;
    else           orem[b * LREM + (r - LKEEP)] = gv;
}

__global__ void copy_misc(const int* __restrict__ git, const float* __restrict__ js,
                          float* __restrict__ out)
{
    int i = blockIdx.x * 256 + threadIdx.x;
    if (i < 2048)      out[O_GIT + i] = (float)git[i];
    else if (i == 2048) out[O_JS] = js[0];
}

__global__ __launch_bounds__(192)
void gather_kernel(const float* __restrict__ X1, const int* __restrict__ ord,
                   float* __restrict__ X1g)
{
    int rowid = blockIdx.x;
    int m   = rowid / (BATCH * NK);
    int rem = rowid - m * (BATCH * NK);
    int b   = rem / NK;
    int r   = rem - b * NK;
    int src = (r < LT) ? r : (LT + ord[b * 256 + (r - LT)]);
    const float4* s = (const float4*)(X1 + ((LL)m * BATCH * NTOK + b * NTOK + src) * 768);
    float4* d = (float4*)(X1g + (LL)rowid * 768);
    d[threadIdx.x] = s[threadIdx.x];
}

// =======================================================================
extern "C" void kernel_launch(void* const* d_in, const int* in_sizes, int n_in,
                              void* d_out, int out_size, void* d_ws, size_t ws_size,
                              hipStream_t stream)
{
    const float* xin_m[2] = { (const float*)d_in[0], (const float*)d_in[1] };
    const int*   git    = (const int*)d_in[2];
    const int*   gis    = (const int*)d_in[3];
    const float* js     = (const float*)d_in[7];
    const float* g1     = (const float*)d_in[8];
    const float* b1     = (const float*)d_in[9];
    const float* w_qkv  = (const float*)d_in[10];
    const float* w_proj = (const float*)d_in[11];
    const float* b_proj = (const float*)d_in[12];
    const float* g2     = (const float*)d_in[13];
    const float* b2     = (const float*)d_in[14];
    const float* w_fc1  = (const float*)d_in[15];
    const float* b_fc1  = (const float*)d_in[16];
    const float* w_fc2  = (const float*)d_in[17];
    const float* b_fc2  = (const float*)d_in[18];

    float* out = (float*)d_out;
    float* ws  = (float*)d_ws;

    float*   QKV  = ws + W_QKV;
    double*  sc   = (double*)(ws + W_SC);
    int*     ord  = (int*)(ws + W_ORD);

    // overlays
    ushort_t* Xh     = (ushort_t*)(ws + W_XN);              // LN1 f16 hi
    ushort_t* Xl     = Xh + 7864320;                        // LN1 f16 lo
    ushort_t* ATTb   = (ushort_t*)(ws + W_XN);              // AV bf16 out (Xh dead)
    ushort_t* Wh     = (ushort_t*)(ws + W_ATT);             // w_qkv f16 hi
    ushort_t* Wl     = Wh + 1769472;                        // w_qkv f16 lo
    ushort_t* WPROJb = (ushort_t*)(ws + W_X1G);             // until gather
    ushort_t* WFC1b  = (ushort_t*)(ws + W_ATT);             // MLP stage (Wh dead)
    ushort_t* WFC2b  = (ushort_t*)(ws + W_ATT + 1179648);
    ushort_t* XN2b   = (ushort_t*)(ws + W_XN);              // MLP stage
    ushort_t* H1b    = (ushort_t*)(ws + W_QKV);             // MLP stage

    // weight conversions (w_qkv split used by both modalities)
    f32_to_bf16<<<dim3(576), dim3(256), 0, stream>>>(w_proj, WPROJb, 589824);
    cvt_f16x2<<<dim3(1728), dim3(256), 0, stream>>>(w_qkv, Wh, Wl, 1769472);

    // ---------------- attention stage (per modality) ----------------
    for (int m = 0; m < 2; ++m) {
        const float* xin = xin_m[m];
        float* corr = out + (m ? O_CT : O_CR);
        float* X1m  = ws + W_X1 + (LL)m * BATCH * NTOK * CDIM;

        ln_f16x2<<<dim3(BATCH * NTOK), dim3(256), 0, stream>>>(xin, g1, b1, Xh, Xl);

        // QKV = Xn @ w_qkv^T  — split-f16 3-pass MFMA (near-f32 accuracy)
        gemm_f16x2<<<dim3(18, 80), dim3(256), 0, stream>>>(
            Xh, Xl, Wh, Wl, QKV, 768, 768, 768, 2304);

        // S = Q @ K^T * 0.125 (f32 — ordering/corrmap-critical)
        gemm_f32<true, false><<<dim3(5, 5, BATCH * HEADS), dim3(256), 0, stream>>>(
            QKV, QKV + 768, corr, nullptr, nullptr,
            320, 320, 64, 2304, 2304, 320, 0,
            HEADS, 737280, 64, 737280, 64, 1228800, 102400, 0, 0.125f, 0);

        softmax_kernel<<<dim3(BATCH * HEADS * NTOK / 4), dim3(256), 0, stream>>>(corr);

        // O = A @ V (f32 math, bf16 output directly into ATTb)
        gemm_f32<false, true><<<dim3(1, 5, BATCH * HEADS), dim3(256), 0, stream>>>(
            corr, QKV + 1536, ATTb, nullptr, nullptr,
            320, 64, 320, 320, 2304, 768, 0,
            HEADS, 1228800, 102400, 737280, 64, 245760, 64, 0, 1.0f, 0);

        // X1 = xin + ATTb @ WPROJb^T + b_proj  (bf16 MFMA)
        gemm_mfma<2><<<dim3(6, 80), dim3(256), 0, stream>>>(
            ATTb, WPROJb, X1m, b_proj, xin, 768, 768, 768, 768, 768);
    }

    // ---------------- scoring / top-k / gather ----------------
    score_reduce<<<dim3(BATCH), dim3(256), 0, stream>>>(out + O_CR, out + O_CT, sc);
    rank_kernel<<<dim3(BATCH), dim3(256), 0, stream>>>(sc, gis, ord,
                                                       out + O_GSN, out + O_REM);
    copy_misc<<<dim3(9), dim3(256), 0, stream>>>(git, js, out);
    gather_kernel<<<dim3(2 * BATCH * NK), dim3(192), 0, stream>>>(ws + W_X1, ord, ws + W_X1G);

    // convert MLP weights (W_ATT region free now)
    f32_to_bf16<<<dim3(2304), dim3(256), 0, stream>>>(w_fc1, WFC1b, 2359296);
    f32_to_bf16<<<dim3(2304), dim3(256), 0, stream>>>(w_fc2, WFC2b, 2359296);

    // ---------------- MLP stage (per modality) ----------------
    for (int m = 0; m < 2; ++m) {
        float* X1Gm = ws + W_X1G + (LL)m * BATCH * NK * CDIM;
        float* xout = out + (m ? O_XTIR : O_XRGB);

        ln_kernel<true><<<dim3(BATCH * NK), dim3(256), 0, stream>>>(X1Gm, g2, b2, XN2b);

        // H1 = gelu(XN2b @ WFC1b^T + b_fc1) -> bf16  (7808 x 3072)
        gemm_mfma<1><<<dim3(24, 61), dim3(256), 0, stream>>>(
            XN2b, WFC1b, H1b, b_fc1, nullptr, 768, 768, 768, 3072, 0);

        // x_out = X1g + H1b @ WFC2b^T + b_fc2  (7808 x 768)
        gemm_mfma<2><<<dim3(6, 61), dim3(256), 0, stream>>>(
            H1b, WFC2b, xout, b_fc2, X1Gm, 3072, 3072, 3072, 768, 768);
    }
}

// Round 5
// 1161.964 us; speedup vs baseline: 3.4341x; 1.0541x over previous
//
#include <hip/hip_runtime.h>

typedef long long LL;
typedef unsigned short ushort_t;
typedef __attribute__((ext_vector_type(8))) short bfrag;      // 8 bf16
typedef __attribute__((ext_vector_type(8))) _Float16 hfrag;   // 8 f16
typedef __attribute__((ext_vector_type(4))) float facc;
typedef __attribute__((ext_vector_type(4))) unsigned short us4;

// ---- problem constants ----
constexpr int CDIM  = 768;
constexpr int HEADS = 12;
constexpr int LT    = 64;
constexpr int NTOK  = 320;
constexpr int BATCH = 32;
constexpr int LKEEP = 180;
constexpr int LREM  = 76;
constexpr int NK    = 244;

// ---- d_out element offsets (all f32) ----
constexpr LL O_XRGB = 0;
constexpr LL O_XTIR = 5996544;
constexpr LL O_GIT  = 11993088;
constexpr LL O_GSN  = 11995136;
constexpr LL O_REM  = 12000896;
constexpr LL O_CR   = 12003328;
constexpr LL O_CT   = 51324928;
constexpr LL O_JS   = 90646528;

// ---- workspace float offsets ----
constexpr LL W_X1   = 0;          // X1 f32, 2 modalities (15728640)
constexpr LL W_X1G  = 15728640;   // gathered X1 (WPROJb overlays until gather)
constexpr LL W_SC   = 27721728;   // 32*256 doubles
constexpr LL W_ORD  = 27738112;   // 32*256 ints
constexpr LL W_XN   = 27746304;   // Xh/Xl f16 splits | ATTb | XN2b  (7864320 floats)
constexpr LL W_QKV  = 35610624;   // Q3/K3 f16 splits (6 x 7864320 ushort) | H1b
constexpr LL W_ATT  = 59596800;   // Wh/Wl | Vt(+2000000) | part(+6000000) | WFCb

constexpr LL SZH = 7864320;       // elems of one [b,h,t,d] / [b,h,d,t] buffer

__device__ inline ushort_t cvt_bf16(float f) {
    union { float f; unsigned u; } x; x.f = f;
    unsigned u = x.u + 0x7fffu + ((x.u >> 16) & 1u);
    return (ushort_t)(u >> 16);
}
union h16u { _Float16 h; ushort_t u; };

#define GLL(gp, lp) __builtin_amdgcn_global_load_lds( \
    (const __attribute__((address_space(1))) unsigned int*)(gp), \
    (__attribute__((address_space(3))) unsigned int*)(lp), 16, 0, 0)

// =======================================================================
// LayerNorm -> bf16
// =======================================================================
template<bool B16OUT>
__global__ __launch_bounds__(256)
void ln_kernel(const float* __restrict__ x, const float* __restrict__ g,
               const float* __restrict__ bta, void* __restrict__ y)
{
    LL row = blockIdx.x;
    const float* xr = x + row * 768;
    int t = threadIdx.x;
    float v0 = xr[t], v1 = xr[t + 256], v2 = xr[t + 512];
    __shared__ float red[256];
    red[t] = v0 + v1 + v2;
    __syncthreads();
    for (int s = 128; s; s >>= 1) { if (t < s) red[t] += red[t + s]; __syncthreads(); }
    float mean = red[0] / 768.0f;
    __syncthreads();
    float d0 = v0 - mean, d1 = v1 - mean, d2 = v2 - mean;
    red[t] = d0 * d0 + d1 * d1 + d2 * d2;
    __syncthreads();
    for (int s = 128; s; s >>= 1) { if (t < s) red[t] += red[t + s]; __syncthreads(); }
    float var = red[0] / 768.0f;
    float rs = 1.0f / sqrtf(var + 1e-5f);
    float o0 = d0 * rs * g[t]       + bta[t];
    float o1 = d1 * rs * g[t + 256] + bta[t + 256];
    float o2 = d2 * rs * g[t + 512] + bta[t + 512];
    if (B16OUT) {
        ushort_t* yr = (ushort_t*)y + row * 768;
        yr[t] = cvt_bf16(o0); yr[t + 256] = cvt_bf16(o1); yr[t + 512] = cvt_bf16(o2);
    } else {
        float* yr = (float*)y + row * 768;
        yr[t] = o0; yr[t + 256] = o1; yr[t + 512] = o2;
    }
}

// =======================================================================
// LayerNorm -> f16 hi/lo split (QKV GEMM A-operand)
// =======================================================================
__global__ __launch_bounds__(256)
void ln_f16x2(const float* __restrict__ x, const float* __restrict__ g,
              const float* __restrict__ bta,
              ushort_t* __restrict__ yh, ushort_t* __restrict__ yl)
{
    LL row = blockIdx.x;
    const float* xr = x + row * 768;
    int t = threadIdx.x;
    float v0 = xr[t], v1 = xr[t + 256], v2 = xr[t + 512];
    __shared__ float red[256];
    red[t] = v0 + v1 + v2;
    __syncthreads();
    for (int s = 128; s; s >>= 1) { if (t < s) red[t] += red[t + s]; __syncthreads(); }
    float mean = red[0] / 768.0f;
    __syncthreads();
    float d0 = v0 - mean, d1 = v1 - mean, d2 = v2 - mean;
    red[t] = d0 * d0 + d1 * d1 + d2 * d2;
    __syncthreads();
    for (int s = 128; s; s >>= 1) { if (t < s) red[t] += red[t + s]; __syncthreads(); }
    float var = red[0] / 768.0f;
    float rs = 1.0f / sqrtf(var + 1e-5f);
    #pragma unroll
    for (int c = 0; c < 3; ++c) {
        float d = (c == 0 ? d0 : c == 1 ? d1 : d2);
        int idx = t + c * 256;
        float o = d * rs * g[idx] + bta[idx];
        h16u hi, lo;
        hi.h = (_Float16)o;
        lo.h = (_Float16)(o - (float)hi.h);
        yh[row * 768 + idx] = hi.u;
        yl[row * 768 + idx] = lo.u;
    }
}

// f32 -> f16 hi/lo split, flat
__global__ __launch_bounds__(256)
void cvt_f16x2(const float* __restrict__ in, ushort_t* __restrict__ oh,
               ushort_t* __restrict__ ol, int n)
{
    int i = (blockIdx.x * 256 + threadIdx.x) * 4;
    if (i >= n) return;
    float4 v = *(const float4*)(in + i);
    us4 h, l;
    #pragma unroll
    for (int j = 0; j < 4; ++j) {
        float f = (j == 0 ? v.x : j == 1 ? v.y : j == 2 ? v.z : v.w);
        h16u hh, ll;
        hh.h = (_Float16)f;
        ll.h = (_Float16)(f - (float)hh.h);
        h[j] = hh.u; l[j] = ll.u;
    }
    *(us4*)(oh + i) = h;
    *(us4*)(ol + i) = l;
}

// =======================================================================
// QKV GEMM: split-f16 3-pass MFMA, epilogue writes Q/K as 3-way f16
// splits [b,h,t,64] and V as bf16 transposed [b,h,64,t].
// =======================================================================
__global__ __launch_bounds__(256)
void gemm_qkv(const ushort_t* __restrict__ Ah, const ushort_t* __restrict__ Al,
              const ushort_t* __restrict__ Bh, const ushort_t* __restrict__ Bl,
              ushort_t* __restrict__ Q1, ushort_t* __restrict__ Q2, ushort_t* __restrict__ Q3,
              ushort_t* __restrict__ K1, ushort_t* __restrict__ K2, ushort_t* __restrict__ K3,
              ushort_t* __restrict__ Vt)
{
    __shared__ ushort_t Ahs[4096], Als[4096], Bhs[4096], Bls[4096];
    const int t = threadIdx.x;
    const int wave = t >> 6, lane = t & 63;
    const int wr = wave >> 1, wc = wave & 1;
    const int lr = lane & 15, lh = lane >> 4;
    const LL bm = (LL)blockIdx.y * 128, bn = (LL)blockIdx.x * 128;

    facc acc[4][4];
    #pragma unroll
    for (int i = 0; i < 4; ++i)
        #pragma unroll
        for (int j = 0; j < 4; ++j) acc[i][j] = (facc)(0.0f);

    const LL soff = (bm + wave * 16 + (lane >> 2)) * (LL)768 + (lane & 3) * 8;
    const LL boff = (bn + wave * 16 + (lane >> 2)) * (LL)768 + (lane & 3) * 8;
    const LL a64 = (LL)64 * 768;

    for (int k0 = 0; k0 < 768; k0 += 32) {
        __syncthreads();
        GLL(Ah + soff + k0,       &Ahs[wave * 512]);
        GLL(Ah + soff + k0 + a64, &Ahs[2048 + wave * 512]);
        GLL(Al + soff + k0,       &Als[wave * 512]);
        GLL(Al + soff + k0 + a64, &Als[2048 + wave * 512]);
        GLL(Bh + boff + k0,       &Bhs[wave * 512]);
        GLL(Bh + boff + k0 + a64, &Bhs[2048 + wave * 512]);
        GLL(Bl + boff + k0,       &Bls[wave * 512]);
        GLL(Bl + boff + k0 + a64, &Bls[2048 + wave * 512]);
        __syncthreads();
        hfrag ah[4], al[4], bh[4], bl[4];
        #pragma unroll
        for (int mi = 0; mi < 4; ++mi) {
            int off = (wr * 64 + mi * 16 + lr) * 32 + lh * 8;
            ah[mi] = *(const hfrag*)&Ahs[off];
            al[mi] = *(const hfrag*)&Als[off];
        }
        #pragma unroll
        for (int ni = 0; ni < 4; ++ni) {
            int off = (wc * 64 + ni * 16 + lr) * 32 + lh * 8;
            bh[ni] = *(const hfrag*)&Bhs[off];
            bl[ni] = *(const hfrag*)&Bls[off];
        }
        #pragma unroll
        for (int mi = 0; mi < 4; ++mi)
            #pragma unroll
            for (int ni = 0; ni < 4; ++ni) {
                acc[mi][ni] = __builtin_amdgcn_mfma_f32_16x16x32_f16(al[mi], bh[ni], acc[mi][ni], 0, 0, 0);
                acc[mi][ni] = __builtin_amdgcn_mfma_f32_16x16x32_f16(ah[mi], bl[ni], acc[mi][ni], 0, 0, 0);
                acc[mi][ni] = __builtin_amdgcn_mfma_f32_16x16x32_f16(ah[mi], bh[ni], acc[mi][ni], 0, 0, 0);
            }
    }

    #pragma unroll
    for (int mi = 0; mi < 4; ++mi)
        #pragma unroll
        for (int ni = 0; ni < 4; ++ni)
            #pragma unroll
            for (int j = 0; j < 4; ++j) {
                int r = (int)bm + wr * 64 + mi * 16 + lh * 4 + j;
                int c = (int)bn + wc * 64 + ni * 16 + lr;
                int b = r / 320, tt = r - b * 320;
                int s = c / 768, rem = c - s * 768;
                int h = rem >> 6, d = rem & 63;
                LL hb = (LL)(b * 12 + h) * 20480;
                float v = acc[mi][ni][j];
                if (s == 2) {
                    Vt[hb + d * 320 + tt] = cvt_bf16(v);
                } else {
                    h16u a1, a2, a3;
                    a1.h = (_Float16)v;
                    float rr = v - (float)a1.h;
                    a2.h = (_Float16)rr;
                    rr -= (float)a2.h;
                    a3.h = (_Float16)rr;
                    LL idx = hb + (LL)tt * 64 + d;
                    if (s == 0) { Q1[idx] = a1.u; Q2[idx] = a2.u; Q3[idx] = a3.u; }
                    else        { K1[idx] = a1.u; K2[idx] = a2.u; K3[idx] = a3.u; }
                }
            }
}

// =======================================================================
// Fused attention: S (6-pass split-f16 MFMA) + softmax + corrmap write
// + AV (bf16 MFMA).  Grid (5, B*H).  LDS 100KB.
// K staged in two 160-token half-rounds (3 splits x 20KB); V (40KB bf16)
// reuses the K0/K1 region; P (bf16, swizzled) in its own 40KB.
// =======================================================================
__global__ __launch_bounds__(256)
void fused_attn(const ushort_t* __restrict__ Qh, const ushort_t* __restrict__ Qm,
                const ushort_t* __restrict__ Ql,
                const ushort_t* __restrict__ Kh, const ushort_t* __restrict__ Km,
                const ushort_t* __restrict__ Kl,
                const ushort_t* __restrict__ Vt,
                float* __restrict__ corr, ushort_t* __restrict__ attb)
{
    __shared__ __align__(128) unsigned char lds[102400];
    constexpr int K0 = 0, K1 = 20480, K2 = 40960, PSOFF = 61440;

    const int t = threadIdx.x;
    const int wave = t >> 6, lane = t & 63;
    const int lr = lane & 15, lh = lane >> 4;
    const int bh = blockIdx.y;
    const int b = bh / 12, h = bh - b * 12;
    const int r0 = blockIdx.x * 64;
    const LL kvbase = (LL)bh * 20480;

    // Q fragments (3 splits x 2 k-halves) straight from global
    const LL qoff = kvbase + (LL)(r0 + wave * 16 + lr) * 64 + lh * 8;
    hfrag qh0 = *(const hfrag*)(Qh + qoff), qh1 = *(const hfrag*)(Qh + qoff + 32);
    hfrag qm0 = *(const hfrag*)(Qm + qoff), qm1 = *(const hfrag*)(Qm + qoff + 32);
    hfrag ql0 = *(const hfrag*)(Ql + qoff), ql1 = *(const hfrag*)(Ql + qoff + 32);

    facc sacc[20];
    #pragma unroll
    for (int ct = 0; ct < 20; ++ct) sacc[ct] = (facc)(0.0f);

    for (int ha = 0; ha < 2; ++ha) {
        if (ha) __syncthreads();           // all waves done reading previous half
        // stage Kh/Km/Kl halves, pre-swizzled source (rule #21)
        #pragma unroll
        for (int i = 0; i < 5; ++i) {
            int chunk = wave * 5 + i;                 // 0..19
            int gs = chunk * 1024 + lane * 16;        // slot byte
            int row = gs >> 7;
            int sb = gs ^ ((row & 7) << 4);
            LL src = kvbase + (LL)ha * 10240 + (sb >> 1);
            GLL(Kh + src, &lds[K0 + chunk * 1024]);
            GLL(Km + src, &lds[K1 + chunk * 1024]);
            GLL(Kl + src, &lds[K2 + chunk * 1024]);
        }
        __syncthreads();                   // staged data visible

        #pragma unroll
        for (int ctl = 0; ctl < 10; ++ctl) {
            int tokl = ctl * 16 + lr;
            int x = (tokl & 7) << 4;
            const unsigned char* kb = lds + tokl * 128;
            int o0 = (lh * 16) ^ x;
            int o1 = (64 + lh * 16) ^ x;
            hfrag kh0 = *(const hfrag*)(kb + K0 + o0);
            hfrag kh1 = *(const hfrag*)(kb + K0 + o1);
            hfrag km0 = *(const hfrag*)(kb + K1 + o0);
            hfrag km1 = *(const hfrag*)(kb + K1 + o1);
            hfrag kl0 = *(const hfrag*)(kb + K2 + o0);
            hfrag kl1 = *(const hfrag*)(kb + K2 + o1);
            int ct = ha * 10 + ctl;
            facc a = sacc[ct];
            a = __builtin_amdgcn_mfma_f32_16x16x32_f16(ql0, kh0, a, 0, 0, 0);
            a = __builtin_amdgcn_mfma_f32_16x16x32_f16(qh0, kl0, a, 0, 0, 0);
            a = __builtin_amdgcn_mfma_f32_16x16x32_f16(qm0, km0, a, 0, 0, 0);
            a = __builtin_amdgcn_mfma_f32_16x16x32_f16(qm0, kh0, a, 0, 0, 0);
            a = __builtin_amdgcn_mfma_f32_16x16x32_f16(qh0, km0, a, 0, 0, 0);
            a = __builtin_amdgcn_mfma_f32_16x16x32_f16(qh0, kh0, a, 0, 0, 0);
            a = __builtin_amdgcn_mfma_f32_16x16x32_f16(ql1, kh1, a, 0, 0, 0);
            a = __builtin_amdgcn_mfma_f32_16x16x32_f16(qh1, kl1, a, 0, 0, 0);
            a = __builtin_amdgcn_mfma_f32_16x16x32_f16(qm1, km1, a, 0, 0, 0);
            a = __builtin_amdgcn_mfma_f32_16x16x32_f16(qm1, kh1, a, 0, 0, 0);
            a = __builtin_amdgcn_mfma_f32_16x16x32_f16(qh1, km1, a, 0, 0, 0);
            a = __builtin_amdgcn_mfma_f32_16x16x32_f16(qh1, kh1, a, 0, 0, 0);
            sacc[ct] = a;
        }
    }

    // ---- softmax (rows = wave*16 + (lane>>4)*4 + j), scale 0.125 ----
    #pragma unroll
    for (int j = 0; j < 4; ++j) {
        float m = sacc[0][j];
        #pragma unroll
        for (int ct = 1; ct < 20; ++ct) m = fmaxf(m, sacc[ct][j]);
        #pragma unroll
        for (int o = 1; o < 16; o <<= 1) m = fmaxf(m, __shfl_xor(m, o, 64));
        m *= 0.125f;
        float s = 0.0f;
        #pragma unroll
        for (int ct = 0; ct < 20; ++ct) {
            float e = expf(sacc[ct][j] * 0.125f - m);
            sacc[ct][j] = e;
            s += e;
        }
        #pragma unroll
        for (int o = 1; o < 16; o <<= 1) s += __shfl_xor(s, o, 64);

        int prow = wave * 16 + (lane >> 4) * 4 + j;
        float* crow = corr + (LL)bh * 102400 + (LL)(r0 + prow) * 320;
        int xr = (prow & 7) << 4;
        #pragma unroll
        for (int ct = 0; ct < 20; ++ct) {
            float p = sacc[ct][j] / s;
            int pcol = ct * 16 + lr;
            crow[pcol] = p;
            *(ushort_t*)(lds + PSOFF + prow * 640 + ((pcol * 2) ^ xr)) = cvt_bf16(p);
        }
    }

    __syncthreads();                       // K reads + P writes complete

    // ---- stage V (bf16, [d,tok]) into K0/K1 region, swizzled ----
    #pragma unroll
    for (int i = 0; i < 10; ++i) {
        int chunk = wave * 10 + i;             // 0..39
        int gs = chunk * 1024 + lane * 16;     // slot byte in 40960
        int d = gs / 640;
        int w = gs - d * 640;
        int sb = d * 640 + (w ^ ((d & 7) << 4));
        GLL(Vt + kvbase + (sb >> 1), &lds[chunk * 1024]);
    }
    __syncthreads();

    // ---- AV: O[64,64] = P[64,320] @ V[320,64] (bf16 MFMA) ----
    facc oacc[4];
    #pragma unroll
    for (int dt = 0; dt < 4; ++dt) oacc[dt] = (facc)(0.0f);
    int prow = wave * 16 + lr;
    int xp = (prow & 7) << 4;
    #pragma unroll
    for (int k0 = 0; k0 < 10; ++k0) {
        bfrag pa = *(const bfrag*)(lds + PSOFF + prow * 640 + ((k0 * 64 + lh * 16) ^ xp));
        #pragma unroll
        for (int dt = 0; dt < 4; ++dt) {
            int dcol = dt * 16 + lr;
            bfrag vb = *(const bfrag*)(lds + dcol * 640 + ((k0 * 64 + lh * 16) ^ ((dcol & 7) << 4)));
            oacc[dt] = __builtin_amdgcn_mfma_f32_16x16x32_bf16(pa, vb, oacc[dt], 0, 0, 0);
        }
    }
    #pragma unroll
    for (int dt = 0; dt < 4; ++dt)
        #pragma unroll
        for (int j = 0; j < 4; ++j) {
            int grow = r0 + wave * 16 + (lane >> 4) * 4 + j;
            int gcol = h * 64 + dt * 16 + lr;
            attb[(LL)(b * 320 + grow) * 768 + gcol] = cvt_bf16(oacc[dt][j]);
        }
}

// =======================================================================
// bf16 MFMA GEMM (proj / fc1 / fc2)
// =======================================================================
template<int EPI>
__global__ __launch_bounds__(256)
void gemm_mfma(const ushort_t* __restrict__ A, const ushort_t* __restrict__ B,
               void* __restrict__ Cv, const float* __restrict__ bias,
               const float* __restrict__ res,
               int K, int lda, int ldb, int ldc, int ldres)
{
    __shared__ ushort_t As[4096];
    __shared__ ushort_t Bs[4096];
    const int t = threadIdx.x;
    const int wave = t >> 6, lane = t & 63;
    const int wr = wave >> 1, wc = wave & 1;
    const LL bm = (LL)blockIdx.y * 128, bn = (LL)blockIdx.x * 128;

    facc acc[4][4];
    #pragma unroll
    for (int i = 0; i < 4; ++i)
        #pragma unroll
        for (int j = 0; j < 4; ++j) acc[i][j] = (facc)(0.0f);

    const int lr = lane & 15, lh = lane >> 4;
    const ushort_t* gA = A + (bm + wave * 16 + (lane >> 2)) * lda + (lane & 3) * 8;
    const ushort_t* gB = B + (bn + wave * 16 + (lane >> 2)) * ldb + (lane & 3) * 8;
    const LL a64 = (LL)64 * lda, b64 = (LL)64 * ldb;

    for (int k0 = 0; k0 < K; k0 += 32) {
        __syncthreads();
        GLL(gA + k0,        &As[wave * 512]);
        GLL(gA + k0 + a64,  &As[2048 + wave * 512]);
        GLL(gB + k0,        &Bs[wave * 512]);
        GLL(gB + k0 + b64,  &Bs[2048 + wave * 512]);
        __syncthreads();
        bfrag a[4], b[4];
        #pragma unroll
        for (int m = 0; m < 4; ++m)
            a[m] = *(const bfrag*)&As[(wr * 64 + m * 16 + lr) * 32 + lh * 8];
        #pragma unroll
        for (int n = 0; n < 4; ++n)
            b[n] = *(const bfrag*)&Bs[(wc * 64 + n * 16 + lr) * 32 + lh * 8];
        #pragma unroll
        for (int m = 0; m < 4; ++m)
            #pragma unroll
            for (int n = 0; n < 4; ++n)
                acc[m][n] = __builtin_amdgcn_mfma_f32_16x16x32_bf16(a[m], b[n], acc[m][n], 0, 0, 0);
    }

    #pragma unroll
    for (int m = 0; m < 4; ++m) {
        #pragma unroll
        for (int n = 0; n < 4; ++n) {
            #pragma unroll
            for (int j = 0; j < 4; ++j) {
                LL r = bm + wr * 64 + m * 16 + lh * 4 + j;
                LL c = bn + wc * 64 + n * 16 + lr;
                float v = acc[m][n][j] + bias[c];
                if (EPI == 1) {
                    v = 0.5f * v * (erff(v * 0.70710678118654752f) + 1.0f);
                    ((ushort_t*)Cv)[r * ldc + c] = cvt_bf16(v);
                } else {
                    v += res[r * ldres + c];
                    ((float*)Cv)[r * ldc + c] = v;
                }
            }
        }
    }
}

__global__ __launch_bounds__(256)
void f32_to_bf16(const float* __restrict__ in, ushort_t* __restrict__ out, int n)
{
    int i = (blockIdx.x * 256 + threadIdx.x) * 4;
    if (i >= n) return;
    float4 v = *(const float4*)(in + i);
    us4 o;
    o[0] = cvt_bf16(v.x); o[1] = cvt_bf16(v.y);
    o[2] = cvt_bf16(v.z); o[3] = cvt_bf16(v.w);
    *(us4*)(out + i) = o;
}

// =======================================================================
// f64 score partials per (b,h), then combine — exact f64 class
// =======================================================================
__global__ __launch_bounds__(256)
void score_partial(const float* __restrict__ c0, const float* __restrict__ c1,
                   double* __restrict__ part)
{
    int bh = blockIdx.x, j = threadIdx.x;
    const float* p0 = c0 + (LL)bh * 102400 + 64 + j;
    const float* p1 = c1 + (LL)bh * 102400 + 64 + j;
    double s = 0.0;
    for (int tq = 0; tq < 64; ++tq)
        s += (double)p0[tq * 320] + (double)p1[tq * 320];
    part[(LL)bh * 256 + j] = s;
}

__global__ __launch_bounds__(256)
void score_combine(const double* __restrict__ part, double* __restrict__ scores)
{
    int b = blockIdx.x, j = threadIdx.x;
    double acc = 0.0;
    for (int h = 0; h < 12; ++h)
        acc += part[(LL)(b * 12 + h) * 256 + j] / 64.0;
    scores[b * 256 + j] = acc / 12.0;
}

__global__ __launch_bounds__(256)
void rank_kernel(const double* __restrict__ scores, const int* __restrict__ gis,
                 int* __restrict__ ord, float* __restrict__ onew, float* __restrict__ orem)
{
    int b = blockIdx.x, j = threadIdx.x;
    __shared__ double s[256];
    s[j] = scores[b * 256 + j];
    __syncthreads();
    double sj = s[j];
    int r = 0;
    for (int i = 0; i < 256; ++i) {
        double si = s[i];
        r += (si > sj) || (si == sj && i < j);
    }
    ord[b * 256 + r] = j;
    float gv = (float)gis[b * 256 + j];
    if (r < LKEEP) onew[b * LKEEP + r] = gv;
    else           orem[b * LREM + (r - LKEEP)] = gv;
}

__global__ void copy_misc(const int* __restrict__ git, const float* __restrict__ js,
                          float* __restrict__ out)
{
    int i = blockIdx.x * 256 + threadIdx.x;
    if (i < 2048)      out[O_GIT + i] = (float)git[i];
    else if (i == 2048) out[O_JS] = js[0];
}

__global__ __launch_bounds__(192)
void gather_kernel(const float* __restrict__ X1, const int* __restrict__ ord,
                   float* __restrict__ X1g)
{
    int rowid = blockIdx.x;
    int m   = rowid / (BATCH * NK);
    int rem = rowid - m * (BATCH * NK);
    int b   = rem / NK;
    int r   = rem - b * NK;
    int src = (r < LT) ? r : (LT + ord[b * 256 + (r - LT)]);
    const float4* s = (const float4*)(X1 + ((LL)m * BATCH * NTOK + b * NTOK + src) * 768);
    float4* d = (float4*)(X1g + (LL)rowid * 768);
    d[threadIdx.x] = s[threadIdx.x];
}

// =======================================================================
extern "C" void kernel_launch(void* const* d_in, const int* in_sizes, int n_in,
                              void* d_out, int out_size, void* d_ws, size_t ws_size,
                              hipStream_t stream)
{
    const float* xin_m[2] = { (const float*)d_in[0], (const float*)d_in[1] };
    const int*   git    = (const int*)d_in[2];
    const int*   gis    = (const int*)d_in[3];
    const float* js     = (const float*)d_in[7];
    const float* g1     = (const float*)d_in[8];
    const float* b1     = (const float*)d_in[9];
    const float* w_qkv  = (const float*)d_in[10];
    const float* w_proj = (const float*)d_in[11];
    const float* b_proj = (const float*)d_in[12];
    const float* g2     = (const float*)d_in[13];
    const float* b2     = (const float*)d_in[14];
    const float* w_fc1  = (const float*)d_in[15];
    const float* b_fc1  = (const float*)d_in[16];
    const float* w_fc2  = (const float*)d_in[17];
    const float* b_fc2  = (const float*)d_in[18];

    float* out = (float*)d_out;
    float* ws  = (float*)d_ws;

    double* sc  = (double*)(ws + W_SC);
    int*    ord = (int*)(ws + W_ORD);

    // overlays
    ushort_t* Xh  = (ushort_t*)(ws + W_XN);
    ushort_t* Xl  = Xh + SZH;
    ushort_t* ATTb = (ushort_t*)(ws + W_XN);           // after QKV gemm
    ushort_t* QK  = (ushort_t*)(ws + W_QKV);
    ushort_t* Qh3 = QK,           *Qm3 = QK + SZH,     *Ql3 = QK + 2 * SZH;
    ushort_t* Kh3 = QK + 3 * SZH, *Km3 = QK + 4 * SZH, *Kl3 = QK + 5 * SZH;
    ushort_t* Wh  = (ushort_t*)(ws + W_ATT);
    ushort_t* Wl  = Wh + 1769472;
    ushort_t* Vt  = (ushort_t*)(ws + W_ATT + 2000000);
    double*   part = (double*)(ws + W_ATT + 6000000);
    ushort_t* WPROJb = (ushort_t*)(ws + W_X1G);        // until gather
    ushort_t* WFC1b  = (ushort_t*)(ws + W_ATT);        // MLP stage
    ushort_t* WFC2b  = (ushort_t*)(ws + W_ATT + 1179648);
    ushort_t* XN2b   = (ushort_t*)(ws + W_XN);         // MLP stage
    ushort_t* H1b    = (ushort_t*)(ws + W_QKV);        // MLP stage

    f32_to_bf16<<<dim3(576), dim3(256), 0, stream>>>(w_proj, WPROJb, 589824);
    cvt_f16x2<<<dim3(1728), dim3(256), 0, stream>>>(w_qkv, Wh, Wl, 1769472);

    // ---------------- attention stage (per modality) ----------------
    for (int m = 0; m < 2; ++m) {
        const float* xin = xin_m[m];
        float* corr = out + (m ? O_CT : O_CR);
        float* X1m  = ws + W_X1 + (LL)m * BATCH * NTOK * CDIM;

        ln_f16x2<<<dim3(BATCH * NTOK), dim3(256), 0, stream>>>(xin, g1, b1, Xh, Xl);

        gemm_qkv<<<dim3(18, 80), dim3(256), 0, stream>>>(
            Xh, Xl, Wh, Wl, Qh3, Qm3, Ql3, Kh3, Km3, Kl3, Vt);

        fused_attn<<<dim3(5, BATCH * HEADS), dim3(256), 0, stream>>>(
            Qh3, Qm3, Ql3, Kh3, Km3, Kl3, Vt, corr, ATTb);

        // X1 = xin + ATTb @ WPROJb^T + b_proj
        gemm_mfma<2><<<dim3(6, 80), dim3(256), 0, stream>>>(
            ATTb, WPROJb, X1m, b_proj, xin, 768, 768, 768, 768, 768);
    }

    // ---------------- scoring / top-k / gather ----------------
    score_partial<<<dim3(BATCH * HEADS), dim3(256), 0, stream>>>(out + O_CR, out + O_CT, part);
    score_combine<<<dim3(BATCH), dim3(256), 0, stream>>>(part, sc);
    rank_kernel<<<dim3(BATCH), dim3(256), 0, stream>>>(sc, gis, ord,
                                                       out + O_GSN, out + O_REM);
    copy_misc<<<dim3(9), dim3(256), 0, stream>>>(git, js, out);
    gather_kernel<<<dim3(2 * BATCH * NK), dim3(192), 0, stream>>>(ws + W_X1, ord, ws + W_X1G);

    f32_to_bf16<<<dim3(2304), dim3(256), 0, stream>>>(w_fc1, WFC1b, 2359296);
    f32_to_bf16<<<dim3(2304), dim3(256), 0, stream>>>(w_fc2, WFC2b, 2359296);

    // ---------------- MLP stage (per modality) ----------------
    for (int m = 0; m < 2; ++m) {
        float* X1Gm = ws + W_X1G + (LL)m * BATCH * NK * CDIM;
        float* xout = out + (m ? O_XTIR : O_XRGB);

        ln_kernel<true><<<dim3(BATCH * NK), dim3(256), 0, stream>>>(X1Gm, g2, b2, XN2b);

        gemm_mfma<1><<<dim3(24, 61), dim3(256), 0, stream>>>(
            XN2b, WFC1b, H1b, b_fc1, nullptr, 768, 768, 768, 3072, 0);

        gemm_mfma<2><<<dim3(6, 61), dim3(256), 0, stream>>>(
            H1b, WFC2b, xout, b_fc2, X1Gm, 3072, 3072, 3072, 768, 768);
    }
}

// Round 6
// 1040.340 us; speedup vs baseline: 3.8356x; 1.1169x over previous
//
#include <hip/hip_runtime.h>

typedef long long LL;
typedef unsigned short ushort_t;
typedef __attribute__((ext_vector_type(8))) short bfrag;      // 8 bf16
typedef __attribute__((ext_vector_type(8))) _Float16 hfrag;   // 8 f16
typedef __attribute__((ext_vector_type(4))) float facc;
typedef __attribute__((ext_vector_type(4))) unsigned short us4;

// ---- problem constants ----
constexpr int CDIM  = 768;
constexpr int HEADS = 12;
constexpr int LT    = 64;
constexpr int NTOK  = 320;
constexpr int BATCH = 32;
constexpr int LKEEP = 180;
constexpr int LREM  = 76;
constexpr int NK    = 244;

// ---- d_out element offsets (all f32) ----
constexpr LL O_XRGB = 0;
constexpr LL O_XTIR = 5996544;
constexpr LL O_GIT  = 11993088;
constexpr LL O_GSN  = 11995136;
constexpr LL O_REM  = 12000896;
constexpr LL O_CR   = 12003328;
constexpr LL O_CT   = 51324928;
constexpr LL O_JS   = 90646528;

// ---- workspace float offsets ----
constexpr LL W_X1   = 0;          // X1 f32, 2 modalities
constexpr LL W_X1G  = 15728640;   // gathered X1 (WPROJb overlays until gather)
constexpr LL W_SC   = 27721728;   // 32*256 doubles
constexpr LL W_ORD  = 27738112;   // 32*256 ints
constexpr LL W_XN   = 27746304;   // Xh/Xl f16 splits | ATTb | XN2b
constexpr LL W_QKV  = 35610624;   // Q3/K3 f16 splits (6 x SZH ushort) | H1b
constexpr LL W_ATT  = 59596800;   // Wh/Wl | Vt(+2000000) | part(+6000000) | WFCb

constexpr LL SZH = 7864320;

__device__ inline ushort_t cvt_bf16(float f) {
    union { float f; unsigned u; } x; x.f = f;
    unsigned u = x.u + 0x7fffu + ((x.u >> 16) & 1u);
    return (ushort_t)(u >> 16);
}
union h16u { _Float16 h; ushort_t u; };

#define GLL(gp, lp) __builtin_amdgcn_global_load_lds( \
    (const __attribute__((address_space(1))) unsigned int*)(gp), \
    (__attribute__((address_space(3))) unsigned int*)(lp), 16, 0, 0)

// =======================================================================
// LayerNorm -> bf16 / f32
// =======================================================================
template<bool B16OUT>
__global__ __launch_bounds__(256)
void ln_kernel(const float* __restrict__ x, const float* __restrict__ g,
               const float* __restrict__ bta, void* __restrict__ y)
{
    LL row = blockIdx.x;
    const float* xr = x + row * 768;
    int t = threadIdx.x;
    float v0 = xr[t], v1 = xr[t + 256], v2 = xr[t + 512];
    __shared__ float red[256];
    red[t] = v0 + v1 + v2;
    __syncthreads();
    for (int s = 128; s; s >>= 1) { if (t < s) red[t] += red[t + s]; __syncthreads(); }
    float mean = red[0] / 768.0f;
    __syncthreads();
    float d0 = v0 - mean, d1 = v1 - mean, d2 = v2 - mean;
    red[t] = d0 * d0 + d1 * d1 + d2 * d2;
    __syncthreads();
    for (int s = 128; s; s >>= 1) { if (t < s) red[t] += red[t + s]; __syncthreads(); }
    float var = red[0] / 768.0f;
    float rs = 1.0f / sqrtf(var + 1e-5f);
    float o0 = d0 * rs * g[t]       + bta[t];
    float o1 = d1 * rs * g[t + 256] + bta[t + 256];
    float o2 = d2 * rs * g[t + 512] + bta[t + 512];
    if (B16OUT) {
        ushort_t* yr = (ushort_t*)y + row * 768;
        yr[t] = cvt_bf16(o0); yr[t + 256] = cvt_bf16(o1); yr[t + 512] = cvt_bf16(o2);
    } else {
        float* yr = (float*)y + row * 768;
        yr[t] = o0; yr[t + 256] = o1; yr[t + 512] = o2;
    }
}

// =======================================================================
// LayerNorm -> f16 hi/lo split
// =======================================================================
__global__ __launch_bounds__(256)
void ln_f16x2(const float* __restrict__ x, const float* __restrict__ g,
              const float* __restrict__ bta,
              ushort_t* __restrict__ yh, ushort_t* __restrict__ yl)
{
    LL row = blockIdx.x;
    const float* xr = x + row * 768;
    int t = threadIdx.x;
    float v0 = xr[t], v1 = xr[t + 256], v2 = xr[t + 512];
    __shared__ float red[256];
    red[t] = v0 + v1 + v2;
    __syncthreads();
    for (int s = 128; s; s >>= 1) { if (t < s) red[t] += red[t + s]; __syncthreads(); }
    float mean = red[0] / 768.0f;
    __syncthreads();
    float d0 = v0 - mean, d1 = v1 - mean, d2 = v2 - mean;
    red[t] = d0 * d0 + d1 * d1 + d2 * d2;
    __syncthreads();
    for (int s = 128; s; s >>= 1) { if (t < s) red[t] += red[t + s]; __syncthreads(); }
    float var = red[0] / 768.0f;
    float rs = 1.0f / sqrtf(var + 1e-5f);
    #pragma unroll
    for (int c = 0; c < 3; ++c) {
        float d = (c == 0 ? d0 : c == 1 ? d1 : d2);
        int idx = t + c * 256;
        float o = d * rs * g[idx] + bta[idx];
        h16u hi, lo;
        hi.h = (_Float16)o;
        lo.h = (_Float16)(o - (float)hi.h);
        yh[row * 768 + idx] = hi.u;
        yl[row * 768 + idx] = lo.u;
    }
}

__global__ __launch_bounds__(256)
void cvt_f16x2(const float* __restrict__ in, ushort_t* __restrict__ oh,
               ushort_t* __restrict__ ol, int n)
{
    int i = (blockIdx.x * 256 + threadIdx.x) * 4;
    if (i >= n) return;
    float4 v = *(const float4*)(in + i);
    us4 h, l;
    #pragma unroll
    for (int j = 0; j < 4; ++j) {
        float f = (j == 0 ? v.x : j == 1 ? v.y : j == 2 ? v.z : v.w);
        h16u hh, ll;
        hh.h = (_Float16)f;
        ll.h = (_Float16)(f - (float)hh.h);
        h[j] = hh.u; l[j] = ll.u;
    }
    *(us4*)(oh + i) = h;
    *(us4*)(ol + i) = l;
}

// =======================================================================
// QKV GEMM: Q/K tiles = 3-pass split-f16 (near-f32); V tiles (bx>=12) =
// single-pass f16 (stored bf16 anyway). Epilogue: Q/K 3-way f16 split
// [b,h,t,64]; V bf16 transposed [b,h,64,t].
// =======================================================================
__global__ __launch_bounds__(256)
void gemm_qkv(const ushort_t* __restrict__ Ah, const ushort_t* __restrict__ Al,
              const ushort_t* __restrict__ Bh, const ushort_t* __restrict__ Bl,
              ushort_t* __restrict__ Q1, ushort_t* __restrict__ Q2, ushort_t* __restrict__ Q3,
              ushort_t* __restrict__ K1, ushort_t* __restrict__ K2, ushort_t* __restrict__ K3,
              ushort_t* __restrict__ Vt)
{
    __shared__ ushort_t Ahs[4096], Als[4096], Bhs[4096], Bls[4096];
    const int t = threadIdx.x;
    const int wave = t >> 6, lane = t & 63;
    const int wr = wave >> 1, wc = wave & 1;
    const int lr = lane & 15, lh = lane >> 4;
    const LL bm = (LL)blockIdx.y * 128, bn = (LL)blockIdx.x * 128;
    const bool vt = (blockIdx.x >= 12);

    facc acc[4][4];
    #pragma unroll
    for (int i = 0; i < 4; ++i)
        #pragma unroll
        for (int j = 0; j < 4; ++j) acc[i][j] = (facc)(0.0f);

    const LL soff = (bm + wave * 16 + (lane >> 2)) * (LL)768 + (lane & 3) * 8;
    const LL boff = (bn + wave * 16 + (lane >> 2)) * (LL)768 + (lane & 3) * 8;
    const LL a64 = (LL)64 * 768;

    for (int k0 = 0; k0 < 768; k0 += 32) {
        __syncthreads();
        GLL(Ah + soff + k0,       &Ahs[wave * 512]);
        GLL(Ah + soff + k0 + a64, &Ahs[2048 + wave * 512]);
        GLL(Bh + boff + k0,       &Bhs[wave * 512]);
        GLL(Bh + boff + k0 + a64, &Bhs[2048 + wave * 512]);
        if (!vt) {
            GLL(Al + soff + k0,       &Als[wave * 512]);
            GLL(Al + soff + k0 + a64, &Als[2048 + wave * 512]);
            GLL(Bl + boff + k0,       &Bls[wave * 512]);
            GLL(Bl + boff + k0 + a64, &Bls[2048 + wave * 512]);
        }
        __syncthreads();
        hfrag ah[4], bh[4];
        #pragma unroll
        for (int mi = 0; mi < 4; ++mi)
            ah[mi] = *(const hfrag*)&Ahs[(wr * 64 + mi * 16 + lr) * 32 + lh * 8];
        #pragma unroll
        for (int ni = 0; ni < 4; ++ni)
            bh[ni] = *(const hfrag*)&Bhs[(wc * 64 + ni * 16 + lr) * 32 + lh * 8];
        if (!vt) {
            hfrag al[4], bl[4];
            #pragma unroll
            for (int mi = 0; mi < 4; ++mi)
                al[mi] = *(const hfrag*)&Als[(wr * 64 + mi * 16 + lr) * 32 + lh * 8];
            #pragma unroll
            for (int ni = 0; ni < 4; ++ni)
                bl[ni] = *(const hfrag*)&Bls[(wc * 64 + ni * 16 + lr) * 32 + lh * 8];
            #pragma unroll
            for (int mi = 0; mi < 4; ++mi)
                #pragma unroll
                for (int ni = 0; ni < 4; ++ni) {
                    acc[mi][ni] = __builtin_amdgcn_mfma_f32_16x16x32_f16(al[mi], bh[ni], acc[mi][ni], 0, 0, 0);
                    acc[mi][ni] = __builtin_amdgcn_mfma_f32_16x16x32_f16(ah[mi], bl[ni], acc[mi][ni], 0, 0, 0);
                    acc[mi][ni] = __builtin_amdgcn_mfma_f32_16x16x32_f16(ah[mi], bh[ni], acc[mi][ni], 0, 0, 0);
                }
        } else {
            #pragma unroll
            for (int mi = 0; mi < 4; ++mi)
                #pragma unroll
                for (int ni = 0; ni < 4; ++ni)
                    acc[mi][ni] = __builtin_amdgcn_mfma_f32_16x16x32_f16(ah[mi], bh[ni], acc[mi][ni], 0, 0, 0);
        }
    }

    #pragma unroll
    for (int mi = 0; mi < 4; ++mi)
        #pragma unroll
        for (int ni = 0; ni < 4; ++ni)
            #pragma unroll
            for (int j = 0; j < 4; ++j) {
                int r = (int)bm + wr * 64 + mi * 16 + lh * 4 + j;
                int c = (int)bn + wc * 64 + ni * 16 + lr;
                int b = r / 320, tt = r - b * 320;
                int s = c / 768, rem = c - s * 768;
                int h = rem >> 6, d = rem & 63;
                LL hb = (LL)(b * 12 + h) * 20480;
                float v = acc[mi][ni][j];
                if (s == 2) {
                    Vt[hb + d * 320 + tt] = cvt_bf16(v);
                } else {
                    h16u a1, a2, a3;
                    a1.h = (_Float16)v;
                    float rr = v - (float)a1.h;
                    a2.h = (_Float16)rr;
                    rr -= (float)a2.h;
                    a3.h = (_Float16)rr;
                    LL idx = hb + (LL)tt * 64 + d;
                    if (s == 0) { Q1[idx] = a1.u; Q2[idx] = a2.u; Q3[idx] = a3.u; }
                    else        { K1[idx] = a1.u; K2[idx] = a2.u; K3[idx] = a3.u; }
                }
            }
}

// =======================================================================
// Fused attention v2. Grid (5, B*H). LDS 80KB -> 2 blocks/CU.
// K staged in 5 rounds of 64 tokens (3 splits x 8KB at lds[0..24576));
// V (40KB) prefetched into lds[0..40960) overlapping softmax;
// P bf16 at lds[40960..81920); after AV the full 80KB holds f32 P rows
// for a coalesced corrmap store + fused f64 score partial (bx==0).
// FULLY UNROLLED round loop so sacc stays in registers (rule #20).
// =======================================================================
__global__ __launch_bounds__(256, 2)
void fused_attn(const ushort_t* __restrict__ Qh, const ushort_t* __restrict__ Qm,
                const ushort_t* __restrict__ Ql,
                const ushort_t* __restrict__ Kh, const ushort_t* __restrict__ Km,
                const ushort_t* __restrict__ Kl,
                const ushort_t* __restrict__ Vt,
                float* __restrict__ corr, ushort_t* __restrict__ attb,
                double* __restrict__ part, int mod)
{
    __shared__ __align__(128) unsigned char lds[81920];
    constexpr int PS = 40960;

    const int t = threadIdx.x;
    const int wave = t >> 6, lane = t & 63;
    const int lr = lane & 15, lh = lane >> 4;
    const int bh = blockIdx.y;
    const int b = bh / 12, h = bh - b * 12;
    const int r0 = blockIdx.x * 64;
    const LL kvbase = (LL)bh * 20480;

    const LL qoff = kvbase + (LL)(r0 + wave * 16 + lr) * 64 + lh * 8;
    hfrag qh0 = *(const hfrag*)(Qh + qoff), qh1 = *(const hfrag*)(Qh + qoff + 32);
    hfrag qm0 = *(const hfrag*)(Qm + qoff), qm1 = *(const hfrag*)(Qm + qoff + 32);
    hfrag ql0 = *(const hfrag*)(Ql + qoff), ql1 = *(const hfrag*)(Ql + qoff + 32);

    facc sacc[20];
    #pragma unroll
    for (int ct = 0; ct < 20; ++ct) sacc[ct] = (facc)(0.0f);

    #pragma unroll
    for (int ha = 0; ha < 5; ++ha) {
        if (ha) __syncthreads();           // all waves done reading prev round
        // stage 64 tokens x 3 splits, pre-swizzled source (rule #21)
        #pragma unroll
        for (int i = 0; i < 6; ++i) {
            int id = wave * 6 + i;                 // 0..23
            int s = id >> 3, c = id & 7;
            int local = c * 1024 + lane * 16;
            int row = local >> 7;
            int sb = local ^ ((row & 7) << 4);
            LL src = kvbase + (LL)ha * 4096 + (sb >> 1);
            const ushort_t* kp = (s == 0) ? Kh : (s == 1) ? Km : Kl;
            GLL(kp + src, &lds[s * 8192 + c * 1024]);
        }
        __syncthreads();                   // staged data visible

        #pragma unroll
        for (int ctl = 0; ctl < 4; ++ctl) {
            int tokl = ctl * 16 + lr;
            int x = (tokl & 7) << 4;
            const unsigned char* kb = lds + tokl * 128;
            int o0 = (lh * 16) ^ x;
            int o1 = (64 + lh * 16) ^ x;
            hfrag kh0 = *(const hfrag*)(kb + o0);
            hfrag kh1 = *(const hfrag*)(kb + o1);
            hfrag km0 = *(const hfrag*)(kb + 8192 + o0);
            hfrag km1 = *(const hfrag*)(kb + 8192 + o1);
            hfrag kl0 = *(const hfrag*)(kb + 16384 + o0);
            hfrag kl1 = *(const hfrag*)(kb + 16384 + o1);
            facc a = sacc[ha * 4 + ctl];
            a = __builtin_amdgcn_mfma_f32_16x16x32_f16(ql0, kh0, a, 0, 0, 0);
            a = __builtin_amdgcn_mfma_f32_16x16x32_f16(qh0, kl0, a, 0, 0, 0);
            a = __builtin_amdgcn_mfma_f32_16x16x32_f16(qm0, km0, a, 0, 0, 0);
            a = __builtin_amdgcn_mfma_f32_16x16x32_f16(qm0, kh0, a, 0, 0, 0);
            a = __builtin_amdgcn_mfma_f32_16x16x32_f16(qh0, km0, a, 0, 0, 0);
            a = __builtin_amdgcn_mfma_f32_16x16x32_f16(qh0, kh0, a, 0, 0, 0);
            a = __builtin_amdgcn_mfma_f32_16x16x32_f16(ql1, kh1, a, 0, 0, 0);
            a = __builtin_amdgcn_mfma_f32_16x16x32_f16(qh1, kl1, a, 0, 0, 0);
            a = __builtin_amdgcn_mfma_f32_16x16x32_f16(qm1, km1, a, 0, 0, 0);
            a = __builtin_amdgcn_mfma_f32_16x16x32_f16(qm1, kh1, a, 0, 0, 0);
            a = __builtin_amdgcn_mfma_f32_16x16x32_f16(qh1, km1, a, 0, 0, 0);
            a = __builtin_amdgcn_mfma_f32_16x16x32_f16(qh1, kh1, a, 0, 0, 0);
            sacc[ha * 4 + ctl] = a;
        }
    }

    __syncthreads();                       // K reads complete

    // ---- prefetch V (bf16 [d,tok], swizzled) into lds[0..40960) ----
    #pragma unroll
    for (int i = 0; i < 10; ++i) {
        int chunk = wave * 10 + i;             // 0..39
        int gs = chunk * 1024 + lane * 16;
        int d = gs / 640;
        int w = gs - d * 640;
        int sb = d * 640 + (w ^ ((d & 7) << 4));
        GLL(Vt + kvbase + (sb >> 1), &lds[chunk * 1024]);
    }

    // ---- softmax under the V load; keep e in sacc, write P bf16 ----
    float rs4[4];
    #pragma unroll
    for (int j = 0; j < 4; ++j) {
        float m = sacc[0][j];
        #pragma unroll
        for (int ct = 1; ct < 20; ++ct) m = fmaxf(m, sacc[ct][j]);
        #pragma unroll
        for (int o = 1; o < 16; o <<= 1) m = fmaxf(m, __shfl_xor(m, o, 64));
        m *= 0.125f;
        float s = 0.0f;
        #pragma unroll
        for (int ct = 0; ct < 20; ++ct) {
            float e = expf(sacc[ct][j] * 0.125f - m);
            sacc[ct][j] = e;
            s += e;
        }
        #pragma unroll
        for (int o = 1; o < 16; o <<= 1) s += __shfl_xor(s, o, 64);
        float rs = 1.0f / s;
        rs4[j] = rs;

        int prow = wave * 16 + lh * 4 + j;
        int xr = (prow & 7) << 4;
        #pragma unroll
        for (int ct = 0; ct < 20; ++ct) {
            int pcol = ct * 16 + lr;
            *(ushort_t*)(lds + PS + prow * 640 + ((pcol * 2) ^ xr)) =
                cvt_bf16(sacc[ct][j] * rs);
        }
    }

    __syncthreads();                       // V ready (vmcnt drained) + P visible

    // ---- AV: O[64,64] = P[64,320] @ V[320,64] (bf16 MFMA) ----
    facc oacc[4];
    #pragma unroll
    for (int dt = 0; dt < 4; ++dt) oacc[dt] = (facc)(0.0f);
    int prow2 = wave * 16 + lr;
    int xp = (prow2 & 7) << 4;
    #pragma unroll
    for (int k0 = 0; k0 < 10; ++k0) {
        bfrag pa = *(const bfrag*)(lds + PS + prow2 * 640 + ((k0 * 64 + lh * 16) ^ xp));
        #pragma unroll
        for (int dt = 0; dt < 4; ++dt) {
            int dcol = dt * 16 + lr;
            bfrag vb = *(const bfrag*)(lds + dcol * 640 + ((k0 * 64 + lh * 16) ^ ((dcol & 7) << 4)));
            oacc[dt] = __builtin_amdgcn_mfma_f32_16x16x32_bf16(pa, vb, oacc[dt], 0, 0, 0);
        }
    }
    #pragma unroll
    for (int dt = 0; dt < 4; ++dt)
        #pragma unroll
        for (int j = 0; j < 4; ++j) {
            int grow = r0 + wave * 16 + lh * 4 + j;
            int gcol = h * 64 + dt * 16 + lr;
            attb[(LL)(b * 320 + grow) * 768 + gcol] = cvt_bf16(oacc[dt][j]);
        }

    __syncthreads();                       // all LDS reads (P,V) done

    // ---- stage f32 P rows into full 80KB, then coalesced store ----
    #pragma unroll
    for (int ct = 0; ct < 20; ++ct) {
        int pcol = ct * 16 + lr;
        #pragma unroll
        for (int j = 0; j < 4; ++j) {
            int prow = wave * 16 + lh * 4 + j;
            *(float*)(lds + (prow * 320 + pcol) * 4) = sacc[ct][j] * rs4[j];
        }
    }
    __syncthreads();

    float* crow = corr + (LL)bh * 102400 + (LL)r0 * 320;
    #pragma unroll
    for (int i = 0; i < 20; ++i) {
        int idx = i * 256 + t;                 // 0..5119
        int row = idx / 80, c4 = idx - row * 80;
        float4 v = *(const float4*)(lds + (row * 320 + c4 * 4) * 4);
        *(float4*)(crow + row * 320 + c4 * 4) = v;
    }

    // ---- fused score partial: template rows live in this block (bx==0) ----
    if (blockIdx.x == 0) {
        double s64 = 0.0;
        for (int r = 0; r < 64; ++r)
            s64 += (double)*(const float*)(lds + (r * 320 + 64 + t) * 4);
        part[((LL)mod * 384 + bh) * 256 + t] = s64;
    }
}

// =======================================================================
// bf16 MFMA GEMM (proj / fc1 / fc2)
// =======================================================================
template<int EPI>
__global__ __launch_bounds__(256)
void gemm_mfma(const ushort_t* __restrict__ A, const ushort_t* __restrict__ B,
               void* __restrict__ Cv, const float* __restrict__ bias,
               const float* __restrict__ res,
               int K, int lda, int ldb, int ldc, int ldres)
{
    __shared__ ushort_t As[4096];
    __shared__ ushort_t Bs[4096];
    const int t = threadIdx.x;
    const int wave = t >> 6, lane = t & 63;
    const int wr = wave >> 1, wc = wave & 1;
    const LL bm = (LL)blockIdx.y * 128, bn = (LL)blockIdx.x * 128;

    facc acc[4][4];
    #pragma unroll
    for (int i = 0; i < 4; ++i)
        #pragma unroll
        for (int j = 0; j < 4; ++j) acc[i][j] = (facc)(0.0f);

    const int lr = lane & 15, lh = lane >> 4;
    const ushort_t* gA = A + (bm + wave * 16 + (lane >> 2)) * lda + (lane & 3) * 8;
    const ushort_t* gB = B + (bn + wave * 16 + (lane >> 2)) * ldb + (lane & 3) * 8;
    const LL a64 = (LL)64 * lda, b64 = (LL)64 * ldb;

    for (int k0 = 0; k0 < K; k0 += 32) {
        __syncthreads();
        GLL(gA + k0,        &As[wave * 512]);
        GLL(gA + k0 + a64,  &As[2048 + wave * 512]);
        GLL(gB + k0,        &Bs[wave * 512]);
        GLL(gB + k0 + b64,  &Bs[2048 + wave * 512]);
        __syncthreads();
        bfrag a[4], b[4];
        #pragma unroll
        for (int m = 0; m < 4; ++m)
            a[m] = *(const bfrag*)&As[(wr * 64 + m * 16 + lr) * 32 + lh * 8];
        #pragma unroll
        for (int n = 0; n < 4; ++n)
            b[n] = *(const bfrag*)&Bs[(wc * 64 + n * 16 + lr) * 32 + lh * 8];
        #pragma unroll
        for (int m = 0; m < 4; ++m)
            #pragma unroll
            for (int n = 0; n < 4; ++n)
                acc[m][n] = __builtin_amdgcn_mfma_f32_16x16x32_bf16(a[m], b[n], acc[m][n], 0, 0, 0);
    }

    #pragma unroll
    for (int m = 0; m < 4; ++m) {
        #pragma unroll
        for (int n = 0; n < 4; ++n) {
            #pragma unroll
            for (int j = 0; j < 4; ++j) {
                LL r = bm + wr * 64 + m * 16 + lh * 4 + j;
                LL c = bn + wc * 64 + n * 16 + lr;
                float v = acc[m][n][j] + bias[c];
                if (EPI == 1) {
                    v = 0.5f * v * (erff(v * 0.70710678118654752f) + 1.0f);
                    ((ushort_t*)Cv)[r * ldc + c] = cvt_bf16(v);
                } else {
                    v += res[r * ldres + c];
                    ((float*)Cv)[r * ldc + c] = v;
                }
            }
        }
    }
}

__global__ __launch_bounds__(256)
void f32_to_bf16(const float* __restrict__ in, ushort_t* __restrict__ out, int n)
{
    int i = (blockIdx.x * 256 + threadIdx.x) * 4;
    if (i >= n) return;
    float4 v = *(const float4*)(in + i);
    us4 o;
    o[0] = cvt_bf16(v.x); o[1] = cvt_bf16(v.y);
    o[2] = cvt_bf16(v.z); o[3] = cvt_bf16(v.w);
    *(us4*)(out + i) = o;
}

// =======================================================================
// score combine (f64) + stable rank (ordering-critical)
// =======================================================================
__global__ __launch_bounds__(256)
void score_combine(const double* __restrict__ part, double* __restrict__ scores)
{
    int b = blockIdx.x, j = threadIdx.x;
    double acc = 0.0;
    for (int h = 0; h < 12; ++h) {
        LL i0 = ((LL)(b * 12 + h)) * 256 + j;
        acc += (part[i0] + part[98304 + i0]) / 64.0;
    }
    scores[b * 256 + j] = acc / 12.0;
}

__global__ __launch_bounds__(256)
void rank_kernel(const double* __restrict__ scores, const int* __restrict__ gis,
                 int* __restrict__ ord, float* __restrict__ onew, float* __restrict__ orem)
{
    int b = blockIdx.x, j = threadIdx.x;
    __shared__ double s[256];
    s[j] = scores[b * 256 + j];
    __syncthreads();
    double sj = s[j];
    int r = 0;
    for (int i = 0; i < 256; ++i) {
        double si = s[i];
        r += (si > sj) || (si == sj && i < j);
    }
    ord[b * 256 + r] = j;
    float gv = (float)gis[b * 256 + j];
    if (r < LKEEP) onew[b * LKEEP + r] = gv;
    else           orem[b * LREM + (r - LKEEP)] = gv;
}

__global__ void copy_misc(const int* __restrict__ git, const float* __restrict__ js,
                          float* __restrict__ out)
{
    int i = blockIdx.x * 256 + threadIdx.x;
    if (i < 2048)      out[O_GIT + i] = (float)git[i];
    else if (i == 2048) out[O_JS] = js[0];
}

__global__ __launch_bounds__(192)
void gather_kernel(const float* __restrict__ X1, const int* __restrict__ ord,
                   float* __restrict__ X1g)
{
    int rowid = blockIdx.x;
    int m   = rowid / (BATCH * NK);
    int rem = rowid - m * (BATCH * NK);
    int b   = rem / NK;
    int r   = rem - b * NK;
    int src = (r < LT) ? r : (LT + ord[b * 256 + (r - LT)]);
    const float4* s = (const float4*)(X1 + ((LL)m * BATCH * NTOK + b * NTOK + src) * 768);
    float4* d = (float4*)(X1g + (LL)rowid * 768);
    d[threadIdx.x] = s[threadIdx.x];
}

// =======================================================================
extern "C" void kernel_launch(void* const* d_in, const int* in_sizes, int n_in,
                              void* d_out, int out_size, void* d_ws, size_t ws_size,
                              hipStream_t stream)
{
    const float* xin_m[2] = { (const float*)d_in[0], (const float*)d_in[1] };
    const int*   git    = (const int*)d_in[2];
    const int*   gis    = (const int*)d_in[3];
    const float* js     = (const float*)d_in[7];
    const float* g1     = (const float*)d_in[8];
    const float* b1     = (const float*)d_in[9];
    const float* w_qkv  = (const float*)d_in[10];
    const float* w_proj = (const float*)d_in[11];
    const float* b_proj = (const float*)d_in[12];
    const float* g2     = (const float*)d_in[13];
    const float* b2     = (const float*)d_in[14];
    const float* w_fc1  = (const float*)d_in[15];
    const float* b_fc1  = (const float*)d_in[16];
    const float* w_fc2  = (const float*)d_in[17];
    const float* b_fc2  = (const float*)d_in[18];

    float* out = (float*)d_out;
    float* ws  = (float*)d_ws;

    double* sc  = (double*)(ws + W_SC);
    int*    ord = (int*)(ws + W_ORD);

    // overlays
    ushort_t* Xh  = (ushort_t*)(ws + W_XN);
    ushort_t* Xl  = Xh + SZH;
    ushort_t* ATTb = (ushort_t*)(ws + W_XN);           // after QKV gemm
    ushort_t* QK  = (ushort_t*)(ws + W_QKV);
    ushort_t* Qh3 = QK,           *Qm3 = QK + SZH,     *Ql3 = QK + 2 * SZH;
    ushort_t* Kh3 = QK + 3 * SZH, *Km3 = QK + 4 * SZH, *Kl3 = QK + 5 * SZH;
    ushort_t* Wh  = (ushort_t*)(ws + W_ATT);
    ushort_t* Wl  = Wh + 1769472;
    ushort_t* Vt  = (ushort_t*)(ws + W_ATT + 2000000);
    double*   part = (double*)(ws + W_ATT + 6000000);  // 2*384*256 doubles
    ushort_t* WPROJb = (ushort_t*)(ws + W_X1G);        // until gather
    ushort_t* WFC1b  = (ushort_t*)(ws + W_ATT);        // MLP stage
    ushort_t* WFC2b  = (ushort_t*)(ws + W_ATT + 1179648);
    ushort_t* XN2b   = (ushort_t*)(ws + W_XN);         // MLP stage
    ushort_t* H1b    = (ushort_t*)(ws + W_QKV);        // MLP stage

    f32_to_bf16<<<dim3(576), dim3(256), 0, stream>>>(w_proj, WPROJb, 589824);
    cvt_f16x2<<<dim3(1728), dim3(256), 0, stream>>>(w_qkv, Wh, Wl, 1769472);

    // ---------------- attention stage (per modality) ----------------
    for (int m = 0; m < 2; ++m) {
        const float* xin = xin_m[m];
        float* corr = out + (m ? O_CT : O_CR);
        float* X1m  = ws + W_X1 + (LL)m * BATCH * NTOK * CDIM;

        ln_f16x2<<<dim3(BATCH * NTOK), dim3(256), 0, stream>>>(xin, g1, b1, Xh, Xl);

        gemm_qkv<<<dim3(18, 80), dim3(256), 0, stream>>>(
            Xh, Xl, Wh, Wl, Qh3, Qm3, Ql3, Kh3, Km3, Kl3, Vt);

        fused_attn<<<dim3(5, BATCH * HEADS), dim3(256), 0, stream>>>(
            Qh3, Qm3, Ql3, Kh3, Km3, Kl3, Vt, corr, ATTb, part, m);

        // X1 = xin + ATTb @ WPROJb^T + b_proj
        gemm_mfma<2><<<dim3(6, 80), dim3(256), 0, stream>>>(
            ATTb, WPROJb, X1m, b_proj, xin, 768, 768, 768, 768, 768);
    }

    // ---------------- scoring / top-k / gather ----------------
    score_combine<<<dim3(BATCH), dim3(256), 0, stream>>>(part, sc);
    rank_kernel<<<dim3(BATCH), dim3(256), 0, stream>>>(sc, gis, ord,
                                                       out + O_GSN, out + O_REM);
    copy_misc<<<dim3(9), dim3(256), 0, stream>>>(git, js, out);
    gather_kernel<<<dim3(2 * BATCH * NK), dim3(192), 0, stream>>>(ws + W_X1, ord, ws + W_X1G);

    f32_to_bf16<<<dim3(2304), dim3(256), 0, stream>>>(w_fc1, WFC1b, 2359296);
    f32_to_bf16<<<dim3(2304), dim3(256), 0, stream>>>(w_fc2, WFC2b, 2359296);

    // ---------------- MLP stage (per modality) ----------------
    for (int m = 0; m < 2; ++m) {
        float* X1Gm = ws + W_X1G + (LL)m * BATCH * NK * CDIM;
        float* xout = out + (m ? O_XTIR : O_XRGB);

        ln_kernel<true><<<dim3(BATCH * NK), dim3(256), 0, stream>>>(X1Gm, g2, b2, XN2b);

        gemm_mfma<1><<<dim3(24, 61), dim3(256), 0, stream>>>(
            XN2b, WFC1b, H1b, b_fc1, nullptr, 768, 768, 768, 3072, 0);

        gemm_mfma<2><<<dim3(6, 61), dim3(256), 0, stream>>>(
            H1b, WFC2b, xout, b_fc2, X1Gm, 3072, 3072, 3072, 768, 768);
    }
}

// Round 7
// 983.306 us; speedup vs baseline: 4.0580x; 1.0580x over previous
//
#include <hip/hip_runtime.h>

typedef long long LL;
typedef unsigned short ushort_t;
typedef __attribute__((ext_vector_type(8))) short bfrag;      // 8 bf16
typedef __attribute__((ext_vector_type(8))) _Float16 hfrag;   // 8 f16
typedef __attribute__((ext_vector_type(4))) float facc;
typedef __attribute__((ext_vector_type(4))) unsigned short us4;

// ---- problem constants ----
constexpr int CDIM  = 768;
constexpr int HEADS = 12;
constexpr int LT    = 64;
constexpr int NTOK  = 320;
constexpr int BATCH = 32;
constexpr int LKEEP = 180;
constexpr int LREM  = 76;
constexpr int NK    = 244;

// ---- d_out element offsets (all f32) ----
constexpr LL O_XRGB = 0;
constexpr LL O_XTIR = 5996544;
constexpr LL O_GIT  = 11993088;
constexpr LL O_GSN  = 11995136;
constexpr LL O_REM  = 12000896;
constexpr LL O_CR   = 12003328;
constexpr LL O_CT   = 51324928;
constexpr LL O_JS   = 90646528;

// ---- workspace float offsets ----
constexpr LL W_X1   = 0;          // X1 f32, 2 modalities
constexpr LL W_X1G  = 15728640;   // gathered X1, 2 modalities contiguous
constexpr LL W_SC   = 27721728;   // 32*256 doubles
constexpr LL W_ORD  = 27738112;   // 32*256 ints
constexpr LL W_XN   = 27746304;   // Xh/Xl f16 | ATTb | XN2b(batched)
constexpr LL W_QKV  = 35610624;   // Q3/K3 f16 splits (6 x SZH ushort) | H1b(batched)
constexpr LL W_ATT  = 59596800;   // Wh/Wl | Vt(+2000000) | part(+6000000) | WFCb

constexpr LL SZH = 7864320;

__device__ inline ushort_t cvt_bf16(float f) {
    union { float f; unsigned u; } x; x.f = f;
    unsigned u = x.u + 0x7fffu + ((x.u >> 16) & 1u);
    return (ushort_t)(u >> 16);
}
union h16u { _Float16 h; ushort_t u; };

#define GLL(gp, lp) __builtin_amdgcn_global_load_lds( \
    (const __attribute__((address_space(1))) unsigned int*)(gp), \
    (__attribute__((address_space(3))) unsigned int*)(lp), 16, 0, 0)

// =======================================================================
// LayerNorm -> bf16 / f32
// =======================================================================
template<bool B16OUT>
__global__ __launch_bounds__(256)
void ln_kernel(const float* __restrict__ x, const float* __restrict__ g,
               const float* __restrict__ bta, void* __restrict__ y)
{
    LL row = blockIdx.x;
    const float* xr = x + row * 768;
    int t = threadIdx.x;
    float v0 = xr[t], v1 = xr[t + 256], v2 = xr[t + 512];
    __shared__ float red[256];
    red[t] = v0 + v1 + v2;
    __syncthreads();
    for (int s = 128; s; s >>= 1) { if (t < s) red[t] += red[t + s]; __syncthreads(); }
    float mean = red[0] / 768.0f;
    __syncthreads();
    float d0 = v0 - mean, d1 = v1 - mean, d2 = v2 - mean;
    red[t] = d0 * d0 + d1 * d1 + d2 * d2;
    __syncthreads();
    for (int s = 128; s; s >>= 1) { if (t < s) red[t] += red[t + s]; __syncthreads(); }
    float var = red[0] / 768.0f;
    float rs = 1.0f / sqrtf(var + 1e-5f);
    float o0 = d0 * rs * g[t]       + bta[t];
    float o1 = d1 * rs * g[t + 256] + bta[t + 256];
    float o2 = d2 * rs * g[t + 512] + bta[t + 512];
    if (B16OUT) {
        ushort_t* yr = (ushort_t*)y + row * 768;
        yr[t] = cvt_bf16(o0); yr[t + 256] = cvt_bf16(o1); yr[t + 512] = cvt_bf16(o2);
    } else {
        float* yr = (float*)y + row * 768;
        yr[t] = o0; yr[t + 256] = o1; yr[t + 512] = o2;
    }
}

// =======================================================================
// LayerNorm -> f16 hi/lo split
// =======================================================================
__global__ __launch_bounds__(256)
void ln_f16x2(const float* __restrict__ x, const float* __restrict__ g,
              const float* __restrict__ bta,
              ushort_t* __restrict__ yh, ushort_t* __restrict__ yl)
{
    LL row = blockIdx.x;
    const float* xr = x + row * 768;
    int t = threadIdx.x;
    float v0 = xr[t], v1 = xr[t + 256], v2 = xr[t + 512];
    __shared__ float red[256];
    red[t] = v0 + v1 + v2;
    __syncthreads();
    for (int s = 128; s; s >>= 1) { if (t < s) red[t] += red[t + s]; __syncthreads(); }
    float mean = red[0] / 768.0f;
    __syncthreads();
    float d0 = v0 - mean, d1 = v1 - mean, d2 = v2 - mean;
    red[t] = d0 * d0 + d1 * d1 + d2 * d2;
    __syncthreads();
    for (int s = 128; s; s >>= 1) { if (t < s) red[t] += red[t + s]; __syncthreads(); }
    float var = red[0] / 768.0f;
    float rs = 1.0f / sqrtf(var + 1e-5f);
    #pragma unroll
    for (int c = 0; c < 3; ++c) {
        float d = (c == 0 ? d0 : c == 1 ? d1 : d2);
        int idx = t + c * 256;
        float o = d * rs * g[idx] + bta[idx];
        h16u hi, lo;
        hi.h = (_Float16)o;
        lo.h = (_Float16)(o - (float)hi.h);
        yh[row * 768 + idx] = hi.u;
        yl[row * 768 + idx] = lo.u;
    }
}

__global__ __launch_bounds__(256)
void cvt_f16x2(const float* __restrict__ in, ushort_t* __restrict__ oh,
               ushort_t* __restrict__ ol, int n)
{
    int i = (blockIdx.x * 256 + threadIdx.x) * 4;
    if (i >= n) return;
    float4 v = *(const float4*)(in + i);
    us4 h, l;
    #pragma unroll
    for (int j = 0; j < 4; ++j) {
        float f = (j == 0 ? v.x : j == 1 ? v.y : j == 2 ? v.z : v.w);
        h16u hh, ll;
        hh.h = (_Float16)f;
        ll.h = (_Float16)(f - (float)hh.h);
        h[j] = hh.u; l[j] = ll.u;
    }
    *(us4*)(oh + i) = h;
    *(us4*)(ol + i) = l;
}

// =======================================================================
// QKV GEMM, 2-phase double-buffered staging (T3-minimum).
// Q/K tiles = 3-pass split-f16; V tiles (bx>=12) = single-pass f16.
// =======================================================================
__global__ __launch_bounds__(256)
void gemm_qkv(const ushort_t* __restrict__ Ah, const ushort_t* __restrict__ Al,
              const ushort_t* __restrict__ Bh, const ushort_t* __restrict__ Bl,
              ushort_t* __restrict__ Q1, ushort_t* __restrict__ Q2, ushort_t* __restrict__ Q3,
              ushort_t* __restrict__ K1, ushort_t* __restrict__ K2, ushort_t* __restrict__ K3,
              ushort_t* __restrict__ Vt)
{
    __shared__ ushort_t Ahs[8192], Als[8192], Bhs[8192], Bls[8192];
    const int t = threadIdx.x;
    const int wave = t >> 6, lane = t & 63;
    const int wr = wave >> 1, wc = wave & 1;
    const int lr = lane & 15, lh = lane >> 4;
    const LL bm = (LL)blockIdx.y * 128, bn = (LL)blockIdx.x * 128;
    const bool vt = (blockIdx.x >= 12);

    facc acc[4][4];
    #pragma unroll
    for (int i = 0; i < 4; ++i)
        #pragma unroll
        for (int j = 0; j < 4; ++j) acc[i][j] = (facc)(0.0f);

    const LL soff = (bm + wave * 16 + (lane >> 2)) * (LL)768 + (lane & 3) * 8;
    const LL boff = (bn + wave * 16 + (lane >> 2)) * (LL)768 + (lane & 3) * 8;
    const LL a64 = (LL)64 * 768;

    // prologue: stage k0=0 into buf 0
    GLL(Ah + soff,       &Ahs[wave * 512]);
    GLL(Ah + soff + a64, &Ahs[2048 + wave * 512]);
    GLL(Bh + boff,       &Bhs[wave * 512]);
    GLL(Bh + boff + a64, &Bhs[2048 + wave * 512]);
    if (!vt) {
        GLL(Al + soff,       &Als[wave * 512]);
        GLL(Al + soff + a64, &Als[2048 + wave * 512]);
        GLL(Bl + boff,       &Bls[wave * 512]);
        GLL(Bl + boff + a64, &Bls[2048 + wave * 512]);
    }
    __syncthreads();

    int cur = 0;
    for (int k0 = 0; k0 < 768; k0 += 32) {
        int nb = (cur ^ 1) * 4096;
        if (k0 + 32 < 768) {            // issue next-tile loads, overlap compute
            GLL(Ah + soff + k0 + 32,       &Ahs[nb + wave * 512]);
            GLL(Ah + soff + k0 + 32 + a64, &Ahs[nb + 2048 + wave * 512]);
            GLL(Bh + boff + k0 + 32,       &Bhs[nb + wave * 512]);
            GLL(Bh + boff + k0 + 32 + a64, &Bhs[nb + 2048 + wave * 512]);
            if (!vt) {
                GLL(Al + soff + k0 + 32,       &Als[nb + wave * 512]);
                GLL(Al + soff + k0 + 32 + a64, &Als[nb + 2048 + wave * 512]);
                GLL(Bl + boff + k0 + 32,       &Bls[nb + wave * 512]);
                GLL(Bl + boff + k0 + 32 + a64, &Bls[nb + 2048 + wave * 512]);
            }
        }
        int cb = cur * 4096;
        hfrag ah[4], bh[4];
        #pragma unroll
        for (int mi = 0; mi < 4; ++mi)
            ah[mi] = *(const hfrag*)&Ahs[cb + (wr * 64 + mi * 16 + lr) * 32 + lh * 8];
        #pragma unroll
        for (int ni = 0; ni < 4; ++ni)
            bh[ni] = *(const hfrag*)&Bhs[cb + (wc * 64 + ni * 16 + lr) * 32 + lh * 8];
        if (!vt) {
            hfrag al[4], bl[4];
            #pragma unroll
            for (int mi = 0; mi < 4; ++mi)
                al[mi] = *(const hfrag*)&Als[cb + (wr * 64 + mi * 16 + lr) * 32 + lh * 8];
            #pragma unroll
            for (int ni = 0; ni < 4; ++ni)
                bl[ni] = *(const hfrag*)&Bls[cb + (wc * 64 + ni * 16 + lr) * 32 + lh * 8];
            #pragma unroll
            for (int mi = 0; mi < 4; ++mi)
                #pragma unroll
                for (int ni = 0; ni < 4; ++ni) {
                    acc[mi][ni] = __builtin_amdgcn_mfma_f32_16x16x32_f16(al[mi], bh[ni], acc[mi][ni], 0, 0, 0);
                    acc[mi][ni] = __builtin_amdgcn_mfma_f32_16x16x32_f16(ah[mi], bl[ni], acc[mi][ni], 0, 0, 0);
                    acc[mi][ni] = __builtin_amdgcn_mfma_f32_16x16x32_f16(ah[mi], bh[ni], acc[mi][ni], 0, 0, 0);
                }
        } else {
            #pragma unroll
            for (int mi = 0; mi < 4; ++mi)
                #pragma unroll
                for (int ni = 0; ni < 4; ++ni)
                    acc[mi][ni] = __builtin_amdgcn_mfma_f32_16x16x32_f16(ah[mi], bh[ni], acc[mi][ni], 0, 0, 0);
        }
        __syncthreads();               // drains prefetch + ds_reads
        cur ^= 1;
    }

    #pragma unroll
    for (int mi = 0; mi < 4; ++mi)
        #pragma unroll
        for (int ni = 0; ni < 4; ++ni)
            #pragma unroll
            for (int j = 0; j < 4; ++j) {
                int r = (int)bm + wr * 64 + mi * 16 + lh * 4 + j;
                int c = (int)bn + wc * 64 + ni * 16 + lr;
                int b = r / 320, tt = r - b * 320;
                int s = c / 768, rem = c - s * 768;
                int h = rem >> 6, d = rem & 63;
                LL hb = (LL)(b * 12 + h) * 20480;
                float v = acc[mi][ni][j];
                if (s == 2) {
                    Vt[hb + d * 320 + tt] = cvt_bf16(v);
                } else {
                    h16u a1, a2, a3;
                    a1.h = (_Float16)v;
                    float rr = v - (float)a1.h;
                    a2.h = (_Float16)rr;
                    rr -= (float)a2.h;
                    a3.h = (_Float16)rr;
                    LL idx = hb + (LL)tt * 64 + d;
                    if (s == 0) { Q1[idx] = a1.u; Q2[idx] = a2.u; Q3[idx] = a3.u; }
                    else        { K1[idx] = a1.u; K2[idx] = a2.u; K3[idx] = a3.u; }
                }
            }
}

// =======================================================================
// Fused attention v3. 1-D grid 1920 with XCD-grouping decode so the 5
// r0-blocks of each (b,h) land on the SAME XCD (K/V re-reads hit L2).
// LDS 80KB -> 2 blocks/CU. Fully unrolled so sacc stays in registers.
// =======================================================================
__global__ __launch_bounds__(256, 2)
void fused_attn(const ushort_t* __restrict__ Qh, const ushort_t* __restrict__ Qm,
                const ushort_t* __restrict__ Ql,
                const ushort_t* __restrict__ Kh, const ushort_t* __restrict__ Km,
                const ushort_t* __restrict__ Kl,
                const ushort_t* __restrict__ Vt,
                float* __restrict__ corr, ushort_t* __restrict__ attb,
                double* __restrict__ part, int mod)
{
    __shared__ __align__(128) unsigned char lds[81920];
    constexpr int PS = 40960;

    const int t = threadIdx.x;
    const int wave = t >> 6, lane = t & 63;
    const int lr = lane & 15, lh = lane >> 4;
    // XCD-group decode: same-bh blocks share id%8 -> same XCD
    const int id  = blockIdx.x;
    const int xcd = id & 7;
    const int rem = id >> 3;           // 0..239
    const int grp = rem / 5;           // 0..47
    const int r0i = rem - grp * 5;     // 0..4
    const int bh  = grp * 8 + xcd;     // 0..383
    const int b = bh / 12, h = bh - b * 12;
    const int r0 = r0i * 64;
    const LL kvbase = (LL)bh * 20480;

    const LL qoff = kvbase + (LL)(r0 + wave * 16 + lr) * 64 + lh * 8;
    hfrag qh0 = *(const hfrag*)(Qh + qoff), qh1 = *(const hfrag*)(Qh + qoff + 32);
    hfrag qm0 = *(const hfrag*)(Qm + qoff), qm1 = *(const hfrag*)(Qm + qoff + 32);
    hfrag ql0 = *(const hfrag*)(Ql + qoff), ql1 = *(const hfrag*)(Ql + qoff + 32);

    facc sacc[20];
    #pragma unroll
    for (int ct = 0; ct < 20; ++ct) sacc[ct] = (facc)(0.0f);

    #pragma unroll
    for (int ha = 0; ha < 5; ++ha) {
        if (ha) __syncthreads();
        #pragma unroll
        for (int i = 0; i < 6; ++i) {
            int id2 = wave * 6 + i;                // 0..23
            int s = id2 >> 3, c = id2 & 7;
            int local = c * 1024 + lane * 16;
            int row = local >> 7;
            int sb = local ^ ((row & 7) << 4);
            LL src = kvbase + (LL)ha * 4096 + (sb >> 1);
            const ushort_t* kp = (s == 0) ? Kh : (s == 1) ? Km : Kl;
            GLL(kp + src, &lds[s * 8192 + c * 1024]);
        }
        __syncthreads();

        #pragma unroll
        for (int ctl = 0; ctl < 4; ++ctl) {
            int tokl = ctl * 16 + lr;
            int x = (tokl & 7) << 4;
            const unsigned char* kb = lds + tokl * 128;
            int o0 = (lh * 16) ^ x;
            int o1 = (64 + lh * 16) ^ x;
            hfrag kh0 = *(const hfrag*)(kb + o0);
            hfrag kh1 = *(const hfrag*)(kb + o1);
            hfrag km0 = *(const hfrag*)(kb + 8192 + o0);
            hfrag km1 = *(const hfrag*)(kb + 8192 + o1);
            hfrag kl0 = *(const hfrag*)(kb + 16384 + o0);
            hfrag kl1 = *(const hfrag*)(kb + 16384 + o1);
            facc a = sacc[ha * 4 + ctl];
            a = __builtin_amdgcn_mfma_f32_16x16x32_f16(ql0, kh0, a, 0, 0, 0);
            a = __builtin_amdgcn_mfma_f32_16x16x32_f16(qh0, kl0, a, 0, 0, 0);
            a = __builtin_amdgcn_mfma_f32_16x16x32_f16(qm0, km0, a, 0, 0, 0);
            a = __builtin_amdgcn_mfma_f32_16x16x32_f16(qm0, kh0, a, 0, 0, 0);
            a = __builtin_amdgcn_mfma_f32_16x16x32_f16(qh0, km0, a, 0, 0, 0);
            a = __builtin_amdgcn_mfma_f32_16x16x32_f16(qh0, kh0, a, 0, 0, 0);
            a = __builtin_amdgcn_mfma_f32_16x16x32_f16(ql1, kh1, a, 0, 0, 0);
            a = __builtin_amdgcn_mfma_f32_16x16x32_f16(qh1, kl1, a, 0, 0, 0);
            a = __builtin_amdgcn_mfma_f32_16x16x32_f16(qm1, km1, a, 0, 0, 0);
            a = __builtin_amdgcn_mfma_f32_16x16x32_f16(qm1, kh1, a, 0, 0, 0);
            a = __builtin_amdgcn_mfma_f32_16x16x32_f16(qh1, km1, a, 0, 0, 0);
            a = __builtin_amdgcn_mfma_f32_16x16x32_f16(qh1, kh1, a, 0, 0, 0);
            sacc[ha * 4 + ctl] = a;
        }
    }

    __syncthreads();

    // prefetch V (bf16 [d,tok], swizzled) into lds[0..40960)
    #pragma unroll
    for (int i = 0; i < 10; ++i) {
        int chunk = wave * 10 + i;
        int gs = chunk * 1024 + lane * 16;
        int d = gs / 640;
        int w = gs - d * 640;
        int sb = d * 640 + (w ^ ((d & 7) << 4));
        GLL(Vt + kvbase + (sb >> 1), &lds[chunk * 1024]);
    }

    // softmax under the V load
    float rs4[4];
    #pragma unroll
    for (int j = 0; j < 4; ++j) {
        float m = sacc[0][j];
        #pragma unroll
        for (int ct = 1; ct < 20; ++ct) m = fmaxf(m, sacc[ct][j]);
        #pragma unroll
        for (int o = 1; o < 16; o <<= 1) m = fmaxf(m, __shfl_xor(m, o, 64));
        m *= 0.125f;
        float s = 0.0f;
        #pragma unroll
        for (int ct = 0; ct < 20; ++ct) {
            float e = expf(sacc[ct][j] * 0.125f - m);
            sacc[ct][j] = e;
            s += e;
        }
        #pragma unroll
        for (int o = 1; o < 16; o <<= 1) s += __shfl_xor(s, o, 64);
        float rs = 1.0f / s;
        rs4[j] = rs;

        int prow = wave * 16 + lh * 4 + j;
        int xr = (prow & 7) << 4;
        #pragma unroll
        for (int ct = 0; ct < 20; ++ct) {
            int pcol = ct * 16 + lr;
            *(ushort_t*)(lds + PS + prow * 640 + ((pcol * 2) ^ xr)) =
                cvt_bf16(sacc[ct][j] * rs);
        }
    }

    __syncthreads();

    // AV: O[64,64] = P[64,320] @ V[320,64]
    facc oacc[4];
    #pragma unroll
    for (int dt = 0; dt < 4; ++dt) oacc[dt] = (facc)(0.0f);
    int prow2 = wave * 16 + lr;
    int xp = (prow2 & 7) << 4;
    #pragma unroll
    for (int k0 = 0; k0 < 10; ++k0) {
        bfrag pa = *(const bfrag*)(lds + PS + prow2 * 640 + ((k0 * 64 + lh * 16) ^ xp));
        #pragma unroll
        for (int dt = 0; dt < 4; ++dt) {
            int dcol = dt * 16 + lr;
            bfrag vb = *(const bfrag*)(lds + dcol * 640 + ((k0 * 64 + lh * 16) ^ ((dcol & 7) << 4)));
            oacc[dt] = __builtin_amdgcn_mfma_f32_16x16x32_bf16(pa, vb, oacc[dt], 0, 0, 0);
        }
    }
    #pragma unroll
    for (int dt = 0; dt < 4; ++dt)
        #pragma unroll
        for (int j = 0; j < 4; ++j) {
            int grow = r0 + wave * 16 + lh * 4 + j;
            int gcol = h * 64 + dt * 16 + lr;
            attb[(LL)(b * 320 + grow) * 768 + gcol] = cvt_bf16(oacc[dt][j]);
        }

    __syncthreads();

    // stage f32 P rows then coalesced corrmap store
    #pragma unroll
    for (int ct = 0; ct < 20; ++ct) {
        int pcol = ct * 16 + lr;
        #pragma unroll
        for (int j = 0; j < 4; ++j) {
            int prow = wave * 16 + lh * 4 + j;
            *(float*)(lds + (prow * 320 + pcol) * 4) = sacc[ct][j] * rs4[j];
        }
    }
    __syncthreads();

    float* crow = corr + (LL)bh * 102400 + (LL)r0 * 320;
    #pragma unroll
    for (int i = 0; i < 20; ++i) {
        int idx = i * 256 + t;
        int row = idx / 80, c4 = idx - row * 80;
        float4 v = *(const float4*)(lds + (row * 320 + c4 * 4) * 4);
        *(float4*)(crow + row * 320 + c4 * 4) = v;
    }

    if (r0i == 0) {
        double s64 = 0.0;
        for (int r = 0; r < 64; ++r)
            s64 += (double)*(const float*)(lds + (r * 320 + 64 + t) * 4);
        part[((LL)mod * 384 + bh) * 256 + t] = s64;
    }
}

// =======================================================================
// bf16 MFMA GEMM (proj / fc1 / fc2), 2-phase double-buffered staging
// =======================================================================
template<int EPI>
__global__ __launch_bounds__(256)
void gemm_mfma(const ushort_t* __restrict__ A, const ushort_t* __restrict__ B,
               void* __restrict__ Cv, const float* __restrict__ bias,
               const float* __restrict__ res,
               int K, int lda, int ldb, int ldc, int ldres)
{
    __shared__ ushort_t As[8192];
    __shared__ ushort_t Bs[8192];
    const int t = threadIdx.x;
    const int wave = t >> 6, lane = t & 63;
    const int wr = wave >> 1, wc = wave & 1;
    const LL bm = (LL)blockIdx.y * 128, bn = (LL)blockIdx.x * 128;

    facc acc[4][4];
    #pragma unroll
    for (int i = 0; i < 4; ++i)
        #pragma unroll
        for (int j = 0; j < 4; ++j) acc[i][j] = (facc)(0.0f);

    const int lr = lane & 15, lh = lane >> 4;
    const ushort_t* gA = A + (bm + wave * 16 + (lane >> 2)) * lda + (lane & 3) * 8;
    const ushort_t* gB = B + (bn + wave * 16 + (lane >> 2)) * ldb + (lane & 3) * 8;
    const LL a64 = (LL)64 * lda, b64 = (LL)64 * ldb;

    // prologue
    GLL(gA,        &As[wave * 512]);
    GLL(gA + a64,  &As[2048 + wave * 512]);
    GLL(gB,        &Bs[wave * 512]);
    GLL(gB + b64,  &Bs[2048 + wave * 512]);
    __syncthreads();

    int cur = 0;
    for (int k0 = 0; k0 < K; k0 += 32) {
        int nb = (cur ^ 1) * 4096;
        if (k0 + 32 < K) {
            GLL(gA + k0 + 32,        &As[nb + wave * 512]);
            GLL(gA + k0 + 32 + a64,  &As[nb + 2048 + wave * 512]);
            GLL(gB + k0 + 32,        &Bs[nb + wave * 512]);
            GLL(gB + k0 + 32 + b64,  &Bs[nb + 2048 + wave * 512]);
        }
        int cb = cur * 4096;
        bfrag a[4], b[4];
        #pragma unroll
        for (int m = 0; m < 4; ++m)
            a[m] = *(const bfrag*)&As[cb + (wr * 64 + m * 16 + lr) * 32 + lh * 8];
        #pragma unroll
        for (int n = 0; n < 4; ++n)
            b[n] = *(const bfrag*)&Bs[cb + (wc * 64 + n * 16 + lr) * 32 + lh * 8];
        #pragma unroll
        for (int m = 0; m < 4; ++m)
            #pragma unroll
            for (int n = 0; n < 4; ++n)
                acc[m][n] = __builtin_amdgcn_mfma_f32_16x16x32_bf16(a[m], b[n], acc[m][n], 0, 0, 0);
        __syncthreads();
        cur ^= 1;
    }

    #pragma unroll
    for (int m = 0; m < 4; ++m) {
        #pragma unroll
        for (int n = 0; n < 4; ++n) {
            #pragma unroll
            for (int j = 0; j < 4; ++j) {
                LL r = bm + wr * 64 + m * 16 + lh * 4 + j;
                LL c = bn + wc * 64 + n * 16 + lr;
                float v = acc[m][n][j] + bias[c];
                if (EPI == 1) {
                    v = 0.5f * v * (erff(v * 0.70710678118654752f) + 1.0f);
                    ((ushort_t*)Cv)[r * ldc + c] = cvt_bf16(v);
                } else {
                    v += res[r * ldres + c];
                    ((float*)Cv)[r * ldc + c] = v;
                }
            }
        }
    }
}

__global__ __launch_bounds__(256)
void f32_to_bf16(const float* __restrict__ in, ushort_t* __restrict__ out, int n)
{
    int i = (blockIdx.x * 256 + threadIdx.x) * 4;
    if (i >= n) return;
    float4 v = *(const float4*)(in + i);
    us4 o;
    o[0] = cvt_bf16(v.x); o[1] = cvt_bf16(v.y);
    o[2] = cvt_bf16(v.z); o[3] = cvt_bf16(v.w);
    *(us4*)(out + i) = o;
}

// =======================================================================
// score combine (f64) + stable rank
// =======================================================================
__global__ __launch_bounds__(256)
void score_combine(const double* __restrict__ part, double* __restrict__ scores)
{
    int b = blockIdx.x, j = threadIdx.x;
    double acc = 0.0;
    for (int h = 0; h < 12; ++h) {
        LL i0 = ((LL)(b * 12 + h)) * 256 + j;
        acc += (part[i0] + part[98304 + i0]) / 64.0;
    }
    scores[b * 256 + j] = acc / 12.0;
}

__global__ __launch_bounds__(256)
void rank_kernel(const double* __restrict__ scores, const int* __restrict__ gis,
                 int* __restrict__ ord, float* __restrict__ onew, float* __restrict__ orem)
{
    int b = blockIdx.x, j = threadIdx.x;
    __shared__ double s[256];
    s[j] = scores[b * 256 + j];
    __syncthreads();
    double sj = s[j];
    int r = 0;
    for (int i = 0; i < 256; ++i) {
        double si = s[i];
        r += (si > sj) || (si == sj && i < j);
    }
    ord[b * 256 + r] = j;
    float gv = (float)gis[b * 256 + j];
    if (r < LKEEP) onew[b * LKEEP + r] = gv;
    else           orem[b * LREM + (r - LKEEP)] = gv;
}

__global__ void copy_misc(const int* __restrict__ git, const float* __restrict__ js,
                          float* __restrict__ out)
{
    int i = blockIdx.x * 256 + threadIdx.x;
    if (i < 2048)      out[O_GIT + i] = (float)git[i];
    else if (i == 2048) out[O_JS] = js[0];
}

__global__ __launch_bounds__(192)
void gather_kernel(const float* __restrict__ X1, const int* __restrict__ ord,
                   float* __restrict__ X1g)
{
    int rowid = blockIdx.x;
    int m   = rowid / (BATCH * NK);
    int rem = rowid - m * (BATCH * NK);
    int b   = rem / NK;
    int r   = rem - b * NK;
    int src = (r < LT) ? r : (LT + ord[b * 256 + (r - LT)]);
    const float4* s = (const float4*)(X1 + ((LL)m * BATCH * NTOK + b * NTOK + src) * 768);
    float4* d = (float4*)(X1g + (LL)rowid * 768);
    d[threadIdx.x] = s[threadIdx.x];
}

// =======================================================================
extern "C" void kernel_launch(void* const* d_in, const int* in_sizes, int n_in,
                              void* d_out, int out_size, void* d_ws, size_t ws_size,
                              hipStream_t stream)
{
    const float* xin_m[2] = { (const float*)d_in[0], (const float*)d_in[1] };
    const int*   git    = (const int*)d_in[2];
    const int*   gis    = (const int*)d_in[3];
    const float* js     = (const float*)d_in[7];
    const float* g1     = (const float*)d_in[8];
    const float* b1     = (const float*)d_in[9];
    const float* w_qkv  = (const float*)d_in[10];
    const float* w_proj = (const float*)d_in[11];
    const float* b_proj = (const float*)d_in[12];
    const float* g2     = (const float*)d_in[13];
    const float* b2     = (const float*)d_in[14];
    const float* w_fc1  = (const float*)d_in[15];
    const float* b_fc1  = (const float*)d_in[16];
    const float* w_fc2  = (const float*)d_in[17];
    const float* b_fc2  = (const float*)d_in[18];

    float* out = (float*)d_out;
    float* ws  = (float*)d_ws;

    double* sc  = (double*)(ws + W_SC);
    int*    ord = (int*)(ws + W_ORD);

    // overlays
    ushort_t* Xh  = (ushort_t*)(ws + W_XN);
    ushort_t* Xl  = Xh + SZH;
    ushort_t* ATTb = (ushort_t*)(ws + W_XN);           // after QKV gemm
    ushort_t* QK  = (ushort_t*)(ws + W_QKV);
    ushort_t* Qh3 = QK,           *Qm3 = QK + SZH,     *Ql3 = QK + 2 * SZH;
    ushort_t* Kh3 = QK + 3 * SZH, *Km3 = QK + 4 * SZH, *Kl3 = QK + 5 * SZH;
    ushort_t* Wh  = (ushort_t*)(ws + W_ATT);
    ushort_t* Wl  = Wh + 1769472;
    ushort_t* Vt  = (ushort_t*)(ws + W_ATT + 2000000);
    double*   part = (double*)(ws + W_ATT + 6000000);
    ushort_t* WPROJb = (ushort_t*)(ws + W_X1G);        // until gather
    ushort_t* WFC1b  = (ushort_t*)(ws + W_ATT);        // MLP stage
    ushort_t* WFC2b  = (ushort_t*)(ws + W_ATT + 1179648);
    ushort_t* XN2b   = (ushort_t*)(ws + W_XN);         // MLP stage (batched)
    ushort_t* H1b    = (ushort_t*)(ws + W_QKV);        // MLP stage (batched)

    f32_to_bf16<<<dim3(576), dim3(256), 0, stream>>>(w_proj, WPROJb, 589824);
    cvt_f16x2<<<dim3(1728), dim3(256), 0, stream>>>(w_qkv, Wh, Wl, 1769472);

    // ---------------- attention stage (per modality) ----------------
    for (int m = 0; m < 2; ++m) {
        const float* xin = xin_m[m];
        float* corr = out + (m ? O_CT : O_CR);
        float* X1m  = ws + W_X1 + (LL)m * BATCH * NTOK * CDIM;

        ln_f16x2<<<dim3(BATCH * NTOK), dim3(256), 0, stream>>>(xin, g1, b1, Xh, Xl);

        gemm_qkv<<<dim3(18, 80), dim3(256), 0, stream>>>(
            Xh, Xl, Wh, Wl, Qh3, Qm3, Ql3, Kh3, Km3, Kl3, Vt);

        fused_attn<<<dim3(1920), dim3(256), 0, stream>>>(
            Qh3, Qm3, Ql3, Kh3, Km3, Kl3, Vt, corr, ATTb, part, m);

        // X1 = xin + ATTb @ WPROJb^T + b_proj
        gemm_mfma<2><<<dim3(6, 80), dim3(256), 0, stream>>>(
            ATTb, WPROJb, X1m, b_proj, xin, 768, 768, 768, 768, 768);
    }

    // ---------------- scoring / top-k / gather ----------------
    score_combine<<<dim3(BATCH), dim3(256), 0, stream>>>(part, sc);
    rank_kernel<<<dim3(BATCH), dim3(256), 0, stream>>>(sc, gis, ord,
                                                       out + O_GSN, out + O_REM);
    copy_misc<<<dim3(9), dim3(256), 0, stream>>>(git, js, out);
    gather_kernel<<<dim3(2 * BATCH * NK), dim3(192), 0, stream>>>(ws + W_X1, ord, ws + W_X1G);

    f32_to_bf16<<<dim3(2304), dim3(256), 0, stream>>>(w_fc1, WFC1b, 2359296);
    f32_to_bf16<<<dim3(2304), dim3(256), 0, stream>>>(w_fc2, WFC2b, 2359296);

    // ---------------- MLP stage (both modalities batched, M=15616) ----
    ln_kernel<true><<<dim3(2 * BATCH * NK), dim3(256), 0, stream>>>(
        ws + W_X1G, g2, b2, XN2b);

    gemm_mfma<1><<<dim3(24, 122), dim3(256), 0, stream>>>(
        XN2b, WFC1b, H1b, b_fc1, nullptr, 768, 768, 768, 3072, 0);

    gemm_mfma<2><<<dim3(6, 122), dim3(256), 0, stream>>>(
        H1b, WFC2b, out + O_XRGB, b_fc2, ws + W_X1G, 3072, 3072, 3072, 768, 768);
}

// Round 8
// 957.707 us; speedup vs baseline: 4.1665x; 1.0267x over previous
//
#include <hip/hip_runtime.h>

typedef long long LL;
typedef unsigned short ushort_t;
typedef __attribute__((ext_vector_type(8))) short bfrag;      // 8 bf16
typedef __attribute__((ext_vector_type(8))) _Float16 hfrag;   // 8 f16
typedef __attribute__((ext_vector_type(4))) float facc;
typedef __attribute__((ext_vector_type(4))) unsigned short us4;

// ---- problem constants ----
constexpr int CDIM  = 768;
constexpr int HEADS = 12;
constexpr int LT    = 64;
constexpr int NTOK  = 320;
constexpr int BATCH = 32;
constexpr int LKEEP = 180;
constexpr int LREM  = 76;
constexpr int NK    = 244;

// ---- d_out element offsets (all f32) ----
constexpr LL O_XRGB = 0;
constexpr LL O_XTIR = 5996544;
constexpr LL O_GIT  = 11993088;
constexpr LL O_GSN  = 11995136;
constexpr LL O_REM  = 12000896;
constexpr LL O_CR   = 12003328;
constexpr LL O_CT   = 51324928;
constexpr LL O_JS   = 90646528;

// ---- workspace float offsets ----
constexpr LL W_X1   = 0;          // X1 f32, 2 modalities
constexpr LL W_X1G  = 15728640;   // WPROJb overlay (gather pass removed)
constexpr LL W_SC   = 27721728;   // 32*256 doubles
constexpr LL W_ORD  = 27738112;   // 32*256 ints
constexpr LL W_XN   = 27746304;   // Xh/Xl f16 | ATTb | (free)
constexpr LL W_QKV  = 35610624;   // Qh/Qm/Kh/Km (4 x SZH ushort) | H1b(batched)
constexpr LL W_ATT  = 59596800;   // Wh/Wl | Vt(+2000000) | part(+6000000) | WFCb

constexpr LL SZH = 7864320;

__device__ inline ushort_t cvt_bf16(float f) {
    union { float f; unsigned u; } x; x.f = f;
    unsigned u = x.u + 0x7fffu + ((x.u >> 16) & 1u);
    return (ushort_t)(u >> 16);
}
union h16u { _Float16 h; ushort_t u; };

#define GLL(gp, lp) __builtin_amdgcn_global_load_lds( \
    (const __attribute__((address_space(1))) unsigned int*)(gp), \
    (__attribute__((address_space(3))) unsigned int*)(lp), 16, 0, 0)

// =======================================================================
// LayerNorm -> bf16 / f32 (direct rows)
// =======================================================================
template<bool B16OUT>
__global__ __launch_bounds__(256)
void ln_kernel(const float* __restrict__ x, const float* __restrict__ g,
               const float* __restrict__ bta, void* __restrict__ y)
{
    LL row = blockIdx.x;
    const float* xr = x + row * 768;
    int t = threadIdx.x;
    float v0 = xr[t], v1 = xr[t + 256], v2 = xr[t + 512];
    __shared__ float red[256];
    red[t] = v0 + v1 + v2;
    __syncthreads();
    for (int s = 128; s; s >>= 1) { if (t < s) red[t] += red[t + s]; __syncthreads(); }
    float mean = red[0] / 768.0f;
    __syncthreads();
    float d0 = v0 - mean, d1 = v1 - mean, d2 = v2 - mean;
    red[t] = d0 * d0 + d1 * d1 + d2 * d2;
    __syncthreads();
    for (int s = 128; s; s >>= 1) { if (t < s) red[t] += red[t + s]; __syncthreads(); }
    float var = red[0] / 768.0f;
    float rs = 1.0f / sqrtf(var + 1e-5f);
    float o0 = d0 * rs * g[t]       + bta[t];
    float o1 = d1 * rs * g[t + 256] + bta[t + 256];
    float o2 = d2 * rs * g[t + 512] + bta[t + 512];
    if (B16OUT) {
        ushort_t* yr = (ushort_t*)y + row * 768;
        yr[t] = cvt_bf16(o0); yr[t + 256] = cvt_bf16(o1); yr[t + 512] = cvt_bf16(o2);
    } else {
        float* yr = (float*)y + row * 768;
        yr[t] = o0; yr[t + 256] = o1; yr[t + 512] = o2;
    }
}

// =======================================================================
// LayerNorm with srcmap indirection -> bf16 (MLP stage, fused gather)
// =======================================================================
__global__ __launch_bounds__(256)
void ln_gather(const float* __restrict__ X1, const int* __restrict__ srcmap,
               const float* __restrict__ g, const float* __restrict__ bta,
               ushort_t* __restrict__ y)
{
    int row = blockIdx.x;
    const float* xr = X1 + (LL)srcmap[row] * 768;
    int t = threadIdx.x;
    float v0 = xr[t], v1 = xr[t + 256], v2 = xr[t + 512];
    __shared__ float red[256];
    red[t] = v0 + v1 + v2;
    __syncthreads();
    for (int s = 128; s; s >>= 1) { if (t < s) red[t] += red[t + s]; __syncthreads(); }
    float mean = red[0] / 768.0f;
    __syncthreads();
    float d0 = v0 - mean, d1 = v1 - mean, d2 = v2 - mean;
    red[t] = d0 * d0 + d1 * d1 + d2 * d2;
    __syncthreads();
    for (int s = 128; s; s >>= 1) { if (t < s) red[t] += red[t + s]; __syncthreads(); }
    float var = red[0] / 768.0f;
    float rs = 1.0f / sqrtf(var + 1e-5f);
    ushort_t* yr = y + (LL)row * 768;
    yr[t]       = cvt_bf16(d0 * rs * g[t]       + bta[t]);
    yr[t + 256] = cvt_bf16(d1 * rs * g[t + 256] + bta[t + 256]);
    yr[t + 512] = cvt_bf16(d2 * rs * g[t + 512] + bta[t + 512]);
}

// =======================================================================
// LayerNorm -> f16 hi/lo split
// =======================================================================
__global__ __launch_bounds__(256)
void ln_f16x2(const float* __restrict__ x, const float* __restrict__ g,
              const float* __restrict__ bta,
              ushort_t* __restrict__ yh, ushort_t* __restrict__ yl)
{
    LL row = blockIdx.x;
    const float* xr = x + row * 768;
    int t = threadIdx.x;
    float v0 = xr[t], v1 = xr[t + 256], v2 = xr[t + 512];
    __shared__ float red[256];
    red[t] = v0 + v1 + v2;
    __syncthreads();
    for (int s = 128; s; s >>= 1) { if (t < s) red[t] += red[t + s]; __syncthreads(); }
    float mean = red[0] / 768.0f;
    __syncthreads();
    float d0 = v0 - mean, d1 = v1 - mean, d2 = v2 - mean;
    red[t] = d0 * d0 + d1 * d1 + d2 * d2;
    __syncthreads();
    for (int s = 128; s; s >>= 1) { if (t < s) red[t] += red[t + s]; __syncthreads(); }
    float var = red[0] / 768.0f;
    float rs = 1.0f / sqrtf(var + 1e-5f);
    #pragma unroll
    for (int c = 0; c < 3; ++c) {
        float d = (c == 0 ? d0 : c == 1 ? d1 : d2);
        int idx = t + c * 256;
        float o = d * rs * g[idx] + bta[idx];
        h16u hi, lo;
        hi.h = (_Float16)o;
        lo.h = (_Float16)(o - (float)hi.h);
        yh[row * 768 + idx] = hi.u;
        yl[row * 768 + idx] = lo.u;
    }
}

__global__ __launch_bounds__(256)
void cvt_f16x2(const float* __restrict__ in, ushort_t* __restrict__ oh,
               ushort_t* __restrict__ ol, int n)
{
    int i = (blockIdx.x * 256 + threadIdx.x) * 4;
    if (i >= n) return;
    float4 v = *(const float4*)(in + i);
    us4 h, l;
    #pragma unroll
    for (int j = 0; j < 4; ++j) {
        float f = (j == 0 ? v.x : j == 1 ? v.y : j == 2 ? v.z : v.w);
        h16u hh, ll;
        hh.h = (_Float16)f;
        ll.h = (_Float16)(f - (float)hh.h);
        h[j] = hh.u; l[j] = ll.u;
    }
    *(us4*)(oh + i) = h;
    *(us4*)(ol + i) = l;
}

// =======================================================================
// QKV GEMM, 2-phase dbuf. Q/K tiles = 3-pass split-f16; V tiles (bx>=12)
// = single-pass. Epilogue: Q/K 2-WAY f16 split [b,h,t,64]; V bf16 [b,h,64,t].
// =======================================================================
__global__ __launch_bounds__(256)
void gemm_qkv(const ushort_t* __restrict__ Ah, const ushort_t* __restrict__ Al,
              const ushort_t* __restrict__ Bh, const ushort_t* __restrict__ Bl,
              ushort_t* __restrict__ Q1, ushort_t* __restrict__ Q2,
              ushort_t* __restrict__ K1, ushort_t* __restrict__ K2,
              ushort_t* __restrict__ Vt)
{
    __shared__ ushort_t Ahs[8192], Als[8192], Bhs[8192], Bls[8192];
    const int t = threadIdx.x;
    const int wave = t >> 6, lane = t & 63;
    const int wr = wave >> 1, wc = wave & 1;
    const int lr = lane & 15, lh = lane >> 4;
    const LL bm = (LL)blockIdx.y * 128, bn = (LL)blockIdx.x * 128;
    const bool vt = (blockIdx.x >= 12);

    facc acc[4][4];
    #pragma unroll
    for (int i = 0; i < 4; ++i)
        #pragma unroll
        for (int j = 0; j < 4; ++j) acc[i][j] = (facc)(0.0f);

    const LL soff = (bm + wave * 16 + (lane >> 2)) * (LL)768 + (lane & 3) * 8;
    const LL boff = (bn + wave * 16 + (lane >> 2)) * (LL)768 + (lane & 3) * 8;
    const LL a64 = (LL)64 * 768;

    GLL(Ah + soff,       &Ahs[wave * 512]);
    GLL(Ah + soff + a64, &Ahs[2048 + wave * 512]);
    GLL(Bh + boff,       &Bhs[wave * 512]);
    GLL(Bh + boff + a64, &Bhs[2048 + wave * 512]);
    if (!vt) {
        GLL(Al + soff,       &Als[wave * 512]);
        GLL(Al + soff + a64, &Als[2048 + wave * 512]);
        GLL(Bl + boff,       &Bls[wave * 512]);
        GLL(Bl + boff + a64, &Bls[2048 + wave * 512]);
    }
    __syncthreads();

    int cur = 0;
    for (int k0 = 0; k0 < 768; k0 += 32) {
        int nb = (cur ^ 1) * 4096;
        if (k0 + 32 < 768) {
            GLL(Ah + soff + k0 + 32,       &Ahs[nb + wave * 512]);
            GLL(Ah + soff + k0 + 32 + a64, &Ahs[nb + 2048 + wave * 512]);
            GLL(Bh + boff + k0 + 32,       &Bhs[nb + wave * 512]);
            GLL(Bh + boff + k0 + 32 + a64, &Bhs[nb + 2048 + wave * 512]);
            if (!vt) {
                GLL(Al + soff + k0 + 32,       &Als[nb + wave * 512]);
                GLL(Al + soff + k0 + 32 + a64, &Als[nb + 2048 + wave * 512]);
                GLL(Bl + boff + k0 + 32,       &Bls[nb + wave * 512]);
                GLL(Bl + boff + k0 + 32 + a64, &Bls[nb + 2048 + wave * 512]);
            }
        }
        int cb = cur * 4096;
        hfrag ah[4], bh[4];
        #pragma unroll
        for (int mi = 0; mi < 4; ++mi)
            ah[mi] = *(const hfrag*)&Ahs[cb + (wr * 64 + mi * 16 + lr) * 32 + lh * 8];
        #pragma unroll
        for (int ni = 0; ni < 4; ++ni)
            bh[ni] = *(const hfrag*)&Bhs[cb + (wc * 64 + ni * 16 + lr) * 32 + lh * 8];
        if (!vt) {
            hfrag al[4], bl[4];
            #pragma unroll
            for (int mi = 0; mi < 4; ++mi)
                al[mi] = *(const hfrag*)&Als[cb + (wr * 64 + mi * 16 + lr) * 32 + lh * 8];
            #pragma unroll
            for (int ni = 0; ni < 4; ++ni)
                bl[ni] = *(const hfrag*)&Bls[cb + (wc * 64 + ni * 16 + lr) * 32 + lh * 8];
            #pragma unroll
            for (int mi = 0; mi < 4; ++mi)
                #pragma unroll
                for (int ni = 0; ni < 4; ++ni) {
                    acc[mi][ni] = __builtin_amdgcn_mfma_f32_16x16x32_f16(al[mi], bh[ni], acc[mi][ni], 0, 0, 0);
                    acc[mi][ni] = __builtin_amdgcn_mfma_f32_16x16x32_f16(ah[mi], bl[ni], acc[mi][ni], 0, 0, 0);
                    acc[mi][ni] = __builtin_amdgcn_mfma_f32_16x16x32_f16(ah[mi], bh[ni], acc[mi][ni], 0, 0, 0);
                }
        } else {
            #pragma unroll
            for (int mi = 0; mi < 4; ++mi)
                #pragma unroll
                for (int ni = 0; ni < 4; ++ni)
                    acc[mi][ni] = __builtin_amdgcn_mfma_f32_16x16x32_f16(ah[mi], bh[ni], acc[mi][ni], 0, 0, 0);
        }
        __syncthreads();
        cur ^= 1;
    }

    #pragma unroll
    for (int mi = 0; mi < 4; ++mi)
        #pragma unroll
        for (int ni = 0; ni < 4; ++ni)
            #pragma unroll
            for (int j = 0; j < 4; ++j) {
                int r = (int)bm + wr * 64 + mi * 16 + lh * 4 + j;
                int c = (int)bn + wc * 64 + ni * 16 + lr;
                int b = r / 320, tt = r - b * 320;
                int s = c / 768, rem = c - s * 768;
                int h = rem >> 6, d = rem & 63;
                LL hb = (LL)(b * 12 + h) * 20480;
                float v = acc[mi][ni][j];
                if (s == 2) {
                    Vt[hb + d * 320 + tt] = cvt_bf16(v);
                } else {
                    h16u a1, a2;
                    a1.h = (_Float16)v;
                    a2.h = (_Float16)(v - (float)a1.h);
                    LL idx = hb + (LL)tt * 64 + d;
                    if (s == 0) { Q1[idx] = a1.u; Q2[idx] = a2.u; }
                    else        { K1[idx] = a1.u; K2[idx] = a2.u; }
                }
            }
}

// =======================================================================
// Fused attention v4: 2-way Q/K splits, 3-MFMA S passes.
// Grid 1920 1-D with XCD-grouping decode. LDS 80KB -> 2 blocks/CU.
// =======================================================================
__global__ __launch_bounds__(256, 2)
void fused_attn(const ushort_t* __restrict__ Qh, const ushort_t* __restrict__ Qm,
                const ushort_t* __restrict__ Kh, const ushort_t* __restrict__ Km,
                const ushort_t* __restrict__ Vt,
                float* __restrict__ corr, ushort_t* __restrict__ attb,
                double* __restrict__ part, int mod)
{
    __shared__ __align__(128) unsigned char lds[81920];
    constexpr int PS = 40960;

    const int t = threadIdx.x;
    const int wave = t >> 6, lane = t & 63;
    const int lr = lane & 15, lh = lane >> 4;
    const int id  = blockIdx.x;
    const int xcd = id & 7;
    const int rem = id >> 3;
    const int grp = rem / 5;
    const int r0i = rem - grp * 5;
    const int bh  = grp * 8 + xcd;
    const int b = bh / 12, h = bh - b * 12;
    const int r0 = r0i * 64;
    const LL kvbase = (LL)bh * 20480;

    const LL qoff = kvbase + (LL)(r0 + wave * 16 + lr) * 64 + lh * 8;
    hfrag qh0 = *(const hfrag*)(Qh + qoff), qh1 = *(const hfrag*)(Qh + qoff + 32);
    hfrag qm0 = *(const hfrag*)(Qm + qoff), qm1 = *(const hfrag*)(Qm + qoff + 32);

    facc sacc[20];
    #pragma unroll
    for (int ct = 0; ct < 20; ++ct) sacc[ct] = (facc)(0.0f);

    #pragma unroll
    for (int ha = 0; ha < 5; ++ha) {
        if (ha) __syncthreads();
        // stage 64 tokens x 2 splits (16 chunks of 1KB), swizzled source
        #pragma unroll
        for (int i = 0; i < 4; ++i) {
            int id2 = wave * 4 + i;                // 0..15
            int s = id2 >> 3, c = id2 & 7;
            int local = c * 1024 + lane * 16;
            int row = local >> 7;
            int sb = local ^ ((row & 7) << 4);
            LL src = kvbase + (LL)ha * 4096 + (sb >> 1);
            const ushort_t* kp = (s == 0) ? Kh : Km;
            GLL(kp + src, &lds[s * 8192 + c * 1024]);
        }
        __syncthreads();

        #pragma unroll
        for (int ctl = 0; ctl < 4; ++ctl) {
            int tokl = ctl * 16 + lr;
            int x = (tokl & 7) << 4;
            const unsigned char* kb = lds + tokl * 128;
            int o0 = (lh * 16) ^ x;
            int o1 = (64 + lh * 16) ^ x;
            hfrag kh0 = *(const hfrag*)(kb + o0);
            hfrag kh1 = *(const hfrag*)(kb + o1);
            hfrag km0 = *(const hfrag*)(kb + 8192 + o0);
            hfrag km1 = *(const hfrag*)(kb + 8192 + o1);
            facc a = sacc[ha * 4 + ctl];
            a = __builtin_amdgcn_mfma_f32_16x16x32_f16(qm0, kh0, a, 0, 0, 0);
            a = __builtin_amdgcn_mfma_f32_16x16x32_f16(qh0, km0, a, 0, 0, 0);
            a = __builtin_amdgcn_mfma_f32_16x16x32_f16(qh0, kh0, a, 0, 0, 0);
            a = __builtin_amdgcn_mfma_f32_16x16x32_f16(qm1, kh1, a, 0, 0, 0);
            a = __builtin_amdgcn_mfma_f32_16x16x32_f16(qh1, km1, a, 0, 0, 0);
            a = __builtin_amdgcn_mfma_f32_16x16x32_f16(qh1, kh1, a, 0, 0, 0);
            sacc[ha * 4 + ctl] = a;
        }
    }

    __syncthreads();

    // prefetch V (bf16 [d,tok], swizzled) into lds[0..40960)
    #pragma unroll
    for (int i = 0; i < 10; ++i) {
        int chunk = wave * 10 + i;
        int gs = chunk * 1024 + lane * 16;
        int d = gs / 640;
        int w = gs - d * 640;
        int sb = d * 640 + (w ^ ((d & 7) << 4));
        GLL(Vt + kvbase + (sb >> 1), &lds[chunk * 1024]);
    }

    // softmax under the V load
    float rs4[4];
    #pragma unroll
    for (int j = 0; j < 4; ++j) {
        float m = sacc[0][j];
        #pragma unroll
        for (int ct = 1; ct < 20; ++ct) m = fmaxf(m, sacc[ct][j]);
        #pragma unroll
        for (int o = 1; o < 16; o <<= 1) m = fmaxf(m, __shfl_xor(m, o, 64));
        m *= 0.125f;
        float s = 0.0f;
        #pragma unroll
        for (int ct = 0; ct < 20; ++ct) {
            float e = expf(sacc[ct][j] * 0.125f - m);
            sacc[ct][j] = e;
            s += e;
        }
        #pragma unroll
        for (int o = 1; o < 16; o <<= 1) s += __shfl_xor(s, o, 64);
        float rs = 1.0f / s;
        rs4[j] = rs;

        int prow = wave * 16 + lh * 4 + j;
        int xr = (prow & 7) << 4;
        #pragma unroll
        for (int ct = 0; ct < 20; ++ct) {
            int pcol = ct * 16 + lr;
            *(ushort_t*)(lds + PS + prow * 640 + ((pcol * 2) ^ xr)) =
                cvt_bf16(sacc[ct][j] * rs);
        }
    }

    __syncthreads();

    // AV: O[64,64] = P[64,320] @ V[320,64]
    facc oacc[4];
    #pragma unroll
    for (int dt = 0; dt < 4; ++dt) oacc[dt] = (facc)(0.0f);
    int prow2 = wave * 16 + lr;
    int xp = (prow2 & 7) << 4;
    #pragma unroll
    for (int k0 = 0; k0 < 10; ++k0) {
        bfrag pa = *(const bfrag*)(lds + PS + prow2 * 640 + ((k0 * 64 + lh * 16) ^ xp));
        #pragma unroll
        for (int dt = 0; dt < 4; ++dt) {
            int dcol = dt * 16 + lr;
            bfrag vb = *(const bfrag*)(lds + dcol * 640 + ((k0 * 64 + lh * 16) ^ ((dcol & 7) << 4)));
            oacc[dt] = __builtin_amdgcn_mfma_f32_16x16x32_bf16(pa, vb, oacc[dt], 0, 0, 0);
        }
    }
    #pragma unroll
    for (int dt = 0; dt < 4; ++dt)
        #pragma unroll
        for (int j = 0; j < 4; ++j) {
            int grow = r0 + wave * 16 + lh * 4 + j;
            int gcol = h * 64 + dt * 16 + lr;
            attb[(LL)(b * 320 + grow) * 768 + gcol] = cvt_bf16(oacc[dt][j]);
        }

    __syncthreads();

    // stage f32 P rows then coalesced corrmap store
    #pragma unroll
    for (int ct = 0; ct < 20; ++ct) {
        int pcol = ct * 16 + lr;
        #pragma unroll
        for (int j = 0; j < 4; ++j) {
            int prow = wave * 16 + lh * 4 + j;
            *(float*)(lds + (prow * 320 + pcol) * 4) = sacc[ct][j] * rs4[j];
        }
    }
    __syncthreads();

    float* crow = corr + (LL)bh * 102400 + (LL)r0 * 320;
    #pragma unroll
    for (int i = 0; i < 20; ++i) {
        int idx = i * 256 + t;
        int row = idx / 80, c4 = idx - row * 80;
        float4 v = *(const float4*)(lds + (row * 320 + c4 * 4) * 4);
        *(float4*)(crow + row * 320 + c4 * 4) = v;
    }

    if (r0i == 0) {
        double s64 = 0.0;
        for (int r = 0; r < 64; ++r)
            s64 += (double)*(const float*)(lds + (r * 320 + 64 + t) * 4);
        part[((LL)mod * 384 + bh) * 256 + t] = s64;
    }
}

// =======================================================================
// bf16 MFMA GEMM, 2-phase dbuf. rmap: optional residual-row indirection.
// =======================================================================
template<int EPI>
__global__ __launch_bounds__(256)
void gemm_mfma(const ushort_t* __restrict__ A, const ushort_t* __restrict__ B,
               void* __restrict__ Cv, const float* __restrict__ bias,
               const float* __restrict__ res, const int* __restrict__ rmap,
               int K, int lda, int ldb, int ldc, int ldres)
{
    __shared__ ushort_t As[8192];
    __shared__ ushort_t Bs[8192];
    const int t = threadIdx.x;
    const int wave = t >> 6, lane = t & 63;
    const int wr = wave >> 1, wc = wave & 1;
    const LL bm = (LL)blockIdx.y * 128, bn = (LL)blockIdx.x * 128;

    facc acc[4][4];
    #pragma unroll
    for (int i = 0; i < 4; ++i)
        #pragma unroll
        for (int j = 0; j < 4; ++j) acc[i][j] = (facc)(0.0f);

    const int lr = lane & 15, lh = lane >> 4;
    const ushort_t* gA = A + (bm + wave * 16 + (lane >> 2)) * lda + (lane & 3) * 8;
    const ushort_t* gB = B + (bn + wave * 16 + (lane >> 2)) * ldb + (lane & 3) * 8;
    const LL a64 = (LL)64 * lda, b64 = (LL)64 * ldb;

    GLL(gA,        &As[wave * 512]);
    GLL(gA + a64,  &As[2048 + wave * 512]);
    GLL(gB,        &Bs[wave * 512]);
    GLL(gB + b64,  &Bs[2048 + wave * 512]);
    __syncthreads();

    int cur = 0;
    for (int k0 = 0; k0 < K; k0 += 32) {
        int nb = (cur ^ 1) * 4096;
        if (k0 + 32 < K) {
            GLL(gA + k0 + 32,        &As[nb + wave * 512]);
            GLL(gA + k0 + 32 + a64,  &As[nb + 2048 + wave * 512]);
            GLL(gB + k0 + 32,        &Bs[nb + wave * 512]);
            GLL(gB + k0 + 32 + b64,  &Bs[nb + 2048 + wave * 512]);
        }
        int cb = cur * 4096;
        bfrag a[4], b[4];
        #pragma unroll
        for (int m = 0; m < 4; ++m)
            a[m] = *(const bfrag*)&As[cb + (wr * 64 + m * 16 + lr) * 32 + lh * 8];
        #pragma unroll
        for (int n = 0; n < 4; ++n)
            b[n] = *(const bfrag*)&Bs[cb + (wc * 64 + n * 16 + lr) * 32 + lh * 8];
        #pragma unroll
        for (int m = 0; m < 4; ++m)
            #pragma unroll
            for (int n = 0; n < 4; ++n)
                acc[m][n] = __builtin_amdgcn_mfma_f32_16x16x32_bf16(a[m], b[n], acc[m][n], 0, 0, 0);
        __syncthreads();
        cur ^= 1;
    }

    #pragma unroll
    for (int m = 0; m < 4; ++m) {
        #pragma unroll
        for (int n = 0; n < 4; ++n) {
            #pragma unroll
            for (int j = 0; j < 4; ++j) {
                LL r = bm + wr * 64 + m * 16 + lh * 4 + j;
                LL c = bn + wc * 64 + n * 16 + lr;
                float v = acc[m][n][j] + bias[c];
                if (EPI == 1) {
                    v = 0.5f * v * (erff(v * 0.70710678118654752f) + 1.0f);
                    ((ushort_t*)Cv)[r * ldc + c] = cvt_bf16(v);
                } else {
                    LL rr = rmap ? (LL)rmap[r] : r;
                    v += res[rr * ldres + c];
                    ((float*)Cv)[r * ldc + c] = v;
                }
            }
        }
    }
}

__global__ __launch_bounds__(256)
void f32_to_bf16(const float* __restrict__ in, ushort_t* __restrict__ out, int n)
{
    int i = (blockIdx.x * 256 + threadIdx.x) * 4;
    if (i >= n) return;
    float4 v = *(const float4*)(in + i);
    us4 o;
    o[0] = cvt_bf16(v.x); o[1] = cvt_bf16(v.y);
    o[2] = cvt_bf16(v.z); o[3] = cvt_bf16(v.w);
    *(us4*)(out + i) = o;
}

// =======================================================================
// score combine (f64) + stable rank + srcmap build
// =======================================================================
__global__ __launch_bounds__(256)
void score_combine(const double* __restrict__ part, double* __restrict__ scores)
{
    int b = blockIdx.x, j = threadIdx.x;
    double acc = 0.0;
    for (int h = 0; h < 12; ++h) {
        LL i0 = ((LL)(b * 12 + h)) * 256 + j;
        acc += (part[i0] + part[98304 + i0]) / 64.0;
    }
    scores[b * 256 + j] = acc / 12.0;
}

__global__ __launch_bounds__(256)
void rank_kernel(const double* __restrict__ scores, const int* __restrict__ gis,
                 int* __restrict__ ord, float* __restrict__ onew, float* __restrict__ orem)
{
    int b = blockIdx.x, j = threadIdx.x;
    __shared__ double s[256];
    s[j] = scores[b * 256 + j];
    __syncthreads();
    double sj = s[j];
    int r = 0;
    for (int i = 0; i < 256; ++i) {
        double si = s[i];
        r += (si > sj) || (si == sj && i < j);
    }
    ord[b * 256 + r] = j;
    float gv = (float)gis[b * 256 + j];
    if (r < LKEEP) onew[b * LKEEP + r] = gv;
    else           orem[b * LREM + (r - LKEEP)] = gv;
}

__global__ __launch_bounds__(256)
void build_srcmap(const int* __restrict__ ord, int* __restrict__ srcmap)
{
    int r = blockIdx.x * 256 + threadIdx.x;
    if (r >= 2 * BATCH * NK) return;
    int m = r / (BATCH * NK);
    int rem = r - m * (BATCH * NK);
    int b = rem / NK;
    int rr = rem - b * NK;
    int src = (rr < LT) ? rr : (LT + ord[b * 256 + (rr - LT)]);
    srcmap[r] = m * (BATCH * NTOK) + b * NTOK + src;
}

__global__ void copy_misc(const int* __restrict__ git, const float* __restrict__ js,
                          float* __restrict__ out)
{
    int i = blockIdx.x * 256 + threadIdx.x;
    if (i < 2048)      out[O_GIT + i] = (float)git[i];
    else if (i == 2048) out[O_JS] = js[0];
}

// =======================================================================
extern "C" void kernel_launch(void* const* d_in, const int* in_sizes, int n_in,
                              void* d_out, int out_size, void* d_ws, size_t ws_size,
                              hipStream_t stream)
{
    const float* xin_m[2] = { (const float*)d_in[0], (const float*)d_in[1] };
    const int*   git    = (const int*)d_in[2];
    const int*   gis    = (const int*)d_in[3];
    const float* js     = (const float*)d_in[7];
    const float* g1     = (const float*)d_in[8];
    const float* b1     = (const float*)d_in[9];
    const float* w_qkv  = (const float*)d_in[10];
    const float* w_proj = (const float*)d_in[11];
    const float* b_proj = (const float*)d_in[12];
    const float* g2     = (const float*)d_in[13];
    const float* b2     = (const float*)d_in[14];
    const float* w_fc1  = (const float*)d_in[15];
    const float* b_fc1  = (const float*)d_in[16];
    const float* w_fc2  = (const float*)d_in[17];
    const float* b_fc2  = (const float*)d_in[18];

    float* out = (float*)d_out;
    float* ws  = (float*)d_ws;

    double* sc  = (double*)(ws + W_SC);
    int*    ord = (int*)(ws + W_ORD);

    // overlays
    ushort_t* Xh  = (ushort_t*)(ws + W_XN);
    ushort_t* Xl  = Xh + SZH;
    ushort_t* ATTb = (ushort_t*)(ws + W_XN);           // after QKV gemm
    ushort_t* QK  = (ushort_t*)(ws + W_QKV);
    ushort_t* Qh2 = QK,           *Qm2 = QK + SZH;
    ushort_t* Kh2 = QK + 2 * SZH, *Km2 = QK + 3 * SZH;
    ushort_t* Wh  = (ushort_t*)(ws + W_ATT);
    ushort_t* Wl  = Wh + 1769472;
    ushort_t* Vt  = (ushort_t*)(ws + W_ATT + 2000000);
    double*   part = (double*)(ws + W_ATT + 6000000);  // 2*384*256 doubles
    int*      srcmap = (int*)(ws + W_ATT + 6000000 + 393216);
    ushort_t* WPROJb = (ushort_t*)(ws + W_X1G);
    ushort_t* WFC1b  = (ushort_t*)(ws + W_ATT);        // MLP stage
    ushort_t* WFC2b  = (ushort_t*)(ws + W_ATT + 1179648);
    ushort_t* XN2b   = (ushort_t*)(ws + W_XN);         // MLP stage (batched)
    ushort_t* H1b    = (ushort_t*)(ws + W_QKV);        // MLP stage (batched)

    f32_to_bf16<<<dim3(576), dim3(256), 0, stream>>>(w_proj, WPROJb, 589824);
    cvt_f16x2<<<dim3(1728), dim3(256), 0, stream>>>(w_qkv, Wh, Wl, 1769472);

    // ---------------- attention stage (per modality) ----------------
    for (int m = 0; m < 2; ++m) {
        const float* xin = xin_m[m];
        float* corr = out + (m ? O_CT : O_CR);
        float* X1m  = ws + W_X1 + (LL)m * BATCH * NTOK * CDIM;

        ln_f16x2<<<dim3(BATCH * NTOK), dim3(256), 0, stream>>>(xin, g1, b1, Xh, Xl);

        gemm_qkv<<<dim3(18, 80), dim3(256), 0, stream>>>(
            Xh, Xl, Wh, Wl, Qh2, Qm2, Kh2, Km2, Vt);

        fused_attn<<<dim3(1920), dim3(256), 0, stream>>>(
            Qh2, Qm2, Kh2, Km2, Vt, corr, ATTb, part, m);

        // X1 = xin + ATTb @ WPROJb^T + b_proj
        gemm_mfma<2><<<dim3(6, 80), dim3(256), 0, stream>>>(
            ATTb, WPROJb, X1m, b_proj, xin, nullptr, 768, 768, 768, 768, 768);
    }

    // ---------------- scoring / top-k ----------------
    score_combine<<<dim3(BATCH), dim3(256), 0, stream>>>(part, sc);
    rank_kernel<<<dim3(BATCH), dim3(256), 0, stream>>>(sc, gis, ord,
                                                       out + O_GSN, out + O_REM);
    build_srcmap<<<dim3(61), dim3(256), 0, stream>>>(ord, srcmap);
    copy_misc<<<dim3(9), dim3(256), 0, stream>>>(git, js, out);

    f32_to_bf16<<<dim3(2304), dim3(256), 0, stream>>>(w_fc1, WFC1b, 2359296);
    f32_to_bf16<<<dim3(2304), dim3(256), 0, stream>>>(w_fc2, WFC2b, 2359296);

    // ---------------- MLP stage (both modalities batched, M=15616) ----
    ln_gather<<<dim3(2 * BATCH * NK), dim3(256), 0, stream>>>(
        ws + W_X1, srcmap, g2, b2, XN2b);

    gemm_mfma<1><<<dim3(24, 122), dim3(256), 0, stream>>>(
        XN2b, WFC1b, H1b, b_fc1, nullptr, nullptr, 768, 768, 768, 3072, 0);

    gemm_mfma<2><<<dim3(6, 122), dim3(256), 0, stream>>>(
        H1b, WFC2b, out + O_XRGB, b_fc2, ws + W_X1, srcmap, 3072, 3072, 3072, 768, 768);
}